// Round 1
// baseline (1523.625 us; speedup 1.0000x reference)
//
#include <hip/hip_runtime.h>
#include <hip/hip_bf16.h>

typedef __attribute__((ext_vector_type(4))) float f4;
typedef __attribute__((ext_vector_type(4))) short s4;
typedef __attribute__((ext_vector_type(8))) short s8;

#define SEQ 4096
#define DIM 1024
#define NB 8

__device__ inline short f2bf(float f) {
    __hip_bfloat16 h = __float2bfloat16(f);
    return __builtin_bit_cast(short, h);
}

// LDS tile: 128 rows x 32 k (bf16), row stride 64 B, 4 chunks of 16 B per row.
// XOR swizzle so ds_read_b128 fragment loads are ~conflict-free.
__device__ inline int swz(int row, int c) {
    return c ^ (row & 3) ^ ((row >> 2) & 3);
}

template<bool CONV>
__device__ inline void stage_tile(const void* __restrict__ gsrc, size_t ld,
                                  size_t row0, size_t k0, char* lds, int tid) {
    if constexpr (CONV) {
        const float* g = (const float*)gsrc;
        #pragma unroll
        for (int p = 0; p < 4; ++p) {
            int row = (tid >> 3) + p * 32;
            int c4  = tid & 7;                       // float4 index in 32-k row
            f4 x = *(const f4*)(g + (row0 + row) * ld + k0 + c4 * 4);
            s4 w;
            w[0] = f2bf(x[0]); w[1] = f2bf(x[1]);
            w[2] = f2bf(x[2]); w[3] = f2bf(x[3]);
            int ch = swz(row, c4 >> 1);
            *(s4*)(lds + row * 64 + ch * 16 + (c4 & 1) * 8) = w;
        }
    } else {
        const short* g = (const short*)gsrc;         // bf16 as short
        #pragma unroll
        for (int p = 0; p < 2; ++p) {
            int row = (tid >> 2) + p * 64;
            int c8  = tid & 3;                       // 8-bf16 chunk index
            s8 x = *(const s8*)(g + (row0 + row) * ld + k0 + c8 * 8);
            int ch = swz(row, c8);
            *(s8*)(lds + row * 64 + ch * 16) = x;
        }
    }
}

__device__ inline s8 frag_ld(const char* lds, int row, int kg) {
    int ch = swz(row, kg);
    return *(const s8*)(lds + row * 64 + ch * 16);
}

// C[M,N] = A[M,K] * B[N,K]^T  (+bias), tiles 128x128, BK=32, 4 waves (2x2).
template<bool ACONV, bool BCONV, bool OBF16, bool BIAS>
__global__ __launch_bounds__(256, 2) void gemm_bt_kernel(
    const void* __restrict__ A, size_t lda,
    const void* __restrict__ B, size_t ldb,
    void* __restrict__ C, size_t ldc,
    const float* __restrict__ bias, int kIters)
{
    __shared__ char lsA[128 * 64];
    __shared__ char lsB[128 * 64];
    const int tid  = threadIdx.x;
    const int lane = tid & 63;
    const int wave = tid >> 6;
    const int wr = wave >> 1, wc = wave & 1;
    const size_t tm = (size_t)blockIdx.y * 128;
    const size_t tn = (size_t)blockIdx.x * 128;

    f4 acc[4][4];
    #pragma unroll
    for (int m = 0; m < 4; ++m)
        #pragma unroll
        for (int n = 0; n < 4; ++n)
            acc[m][n] = (f4){0.f, 0.f, 0.f, 0.f};

    const int fr = lane & 15;   // fragment row/col
    const int kg = lane >> 4;   // k-group (8 bf16 each)

    for (int kt = 0; kt < kIters; ++kt) {
        const size_t k0 = (size_t)kt * 32;
        stage_tile<ACONV>(A, lda, tm, k0, lsA, tid);
        stage_tile<BCONV>(B, ldb, tn, k0, lsB, tid);
        __syncthreads();

        s8 af[4], bf[4];
        #pragma unroll
        for (int m = 0; m < 4; ++m) af[m] = frag_ld(lsA, wr * 64 + m * 16 + fr, kg);
        #pragma unroll
        for (int n = 0; n < 4; ++n) bf[n] = frag_ld(lsB, wc * 64 + n * 16 + fr, kg);

        #pragma unroll
        for (int m = 0; m < 4; ++m)
            #pragma unroll
            for (int n = 0; n < 4; ++n)
                acc[m][n] = __builtin_amdgcn_mfma_f32_16x16x32_bf16(af[m], bf[n], acc[m][n], 0, 0, 0);
        __syncthreads();
    }

    // Epilogue. C/D layout: col = lane&15, row = (lane>>4)*4 + i.
    const int cg = lane >> 4;
    const int cl = lane & 15;
    #pragma unroll
    for (int m = 0; m < 4; ++m) {
        #pragma unroll
        for (int n = 0; n < 4; ++n) {
            size_t grow = tm + wr * 64 + m * 16 + cg * 4;
            size_t gcol = tn + wc * 64 + n * 16 + cl;
            float bv = 0.f;
            if constexpr (BIAS) bv = bias[gcol];
            #pragma unroll
            for (int i = 0; i < 4; ++i) {
                float val = acc[m][n][i] + bv;
                if constexpr (OBF16)
                    ((short*)C)[(grow + i) * ldc + gcol] = f2bf(val);
                else
                    ((float*)C)[(grow + i) * ldc + gcol] = val;
            }
        }
    }
}

// Row softmax over 4096 fp32 scores (applies 1/sqrt(D) scale), writes bf16 P
// in place over the start of each row (row byte stride stays 16384).
__global__ __launch_bounds__(256) void softmax_rows(float* __restrict__ scores)
{
    const int tid = threadIdx.x;
    float* srow = scores + (size_t)blockIdx.x * SEQ;
    const float SCALE = 0.03125f;  // 1/sqrt(1024)

    f4 v[4];
    float mx = -3.4e38f;
    #pragma unroll
    for (int j = 0; j < 4; ++j) {
        v[j] = *(const f4*)(srow + (size_t)(j * 256 + tid) * 4);
        #pragma unroll
        for (int i = 0; i < 4; ++i) {
            v[j][i] *= SCALE;
            mx = fmaxf(mx, v[j][i]);
        }
    }
    #pragma unroll
    for (int o = 32; o > 0; o >>= 1) mx = fmaxf(mx, __shfl_xor(mx, o));
    __shared__ float red[4];
    if ((tid & 63) == 0) red[tid >> 6] = mx;
    __syncthreads();
    mx = fmaxf(fmaxf(red[0], red[1]), fmaxf(red[2], red[3]));

    float sum = 0.f;
    #pragma unroll
    for (int j = 0; j < 4; ++j)
        #pragma unroll
        for (int i = 0; i < 4; ++i) {
            float e = __expf(v[j][i] - mx);
            v[j][i] = e;
            sum += e;
        }
    #pragma unroll
    for (int o = 32; o > 0; o >>= 1) sum += __shfl_xor(sum, o);
    __syncthreads();
    if ((tid & 63) == 0) red[tid >> 6] = sum;
    __syncthreads();
    const float inv = 1.f / (red[0] + red[1] + red[2] + red[3]);

    // All loads complete (barriers above) -> safe to overwrite in place.
    short* prow = (short*)srow;
    #pragma unroll
    for (int j = 0; j < 4; ++j) {
        s4 w;
        #pragma unroll
        for (int i = 0; i < 4; ++i) w[i] = f2bf(v[j][i] * inv);
        *(s4*)(prow + (size_t)(j * 256 + tid) * 4) = w;
    }
}

// V[b] fp32 [4096 k][1024 d] -> VT bf16 [1024 d][4096 k], 32x32 tiles.
__global__ __launch_bounds__(256) void transpose_v(const float* __restrict__ V,
                                                   short* __restrict__ VT)
{
    __shared__ float t[32][33];
    const int tid = threadIdx.x;
    const size_t k0 = (size_t)blockIdx.x * 32;
    const size_t d0 = (size_t)blockIdx.y * 32;

    const int r = tid >> 3, c4 = (tid & 7) * 4;
    f4 x = *(const f4*)(V + (k0 + r) * DIM + d0 + c4);
    #pragma unroll
    for (int i = 0; i < 4; ++i) t[r][c4 + i] = x[i];
    __syncthreads();

    const int d = tid >> 3, kk = (tid & 7) * 4;
    s4 w;
    #pragma unroll
    for (int i = 0; i < 4; ++i) w[i] = f2bf(t[kk + i][d]);
    *(s4*)(VT + (d0 + d) * SEQ + k0 + kk) = w;
}

extern "C" void kernel_launch(void* const* d_in, const int* in_sizes, int n_in,
                              void* d_out, int out_size, void* d_ws, size_t ws_size,
                              hipStream_t stream) {
    const float* Q    = (const float*)d_in[0];
    const float* Km   = (const float*)d_in[1];
    const float* V    = (const float*)d_in[2];
    const float* W    = (const float*)d_in[3];
    const float* bias = (const float*)d_in[4];
    float* out = (float*)d_out;

    // ws layout: ctx bf16 [8*4096, 1024] (64 MB) | VT bf16 [1024, 4096] (8 MB)
    short* ctx = (short*)d_ws;
    short* VT  = ctx + (size_t)NB * SEQ * DIM;
    // d_out doubles as per-batch fp32 score scratch (64 MB < 128 MB).
    float* scores = out;

    const dim3 blk(256);
    for (int b = 0; b < NB; ++b) {
        const float* Qb = Q  + (size_t)b * SEQ * DIM;
        const float* Kb = Km + (size_t)b * SEQ * DIM;
        const float* Vb = V  + (size_t)b * SEQ * DIM;
        short* ctxb = ctx + (size_t)b * SEQ * DIM;

        transpose_v<<<dim3(SEQ / 32, DIM / 32), blk, 0, stream>>>(Vb, VT);
        // scores = Qb * Kb^T  (raw fp32, scale applied in softmax)
        gemm_bt_kernel<true, true, false, false>
            <<<dim3(SEQ / 128, SEQ / 128), blk, 0, stream>>>(
                Qb, DIM, Kb, DIM, scores, SEQ, nullptr, DIM / 32);
        softmax_rows<<<dim3(SEQ), blk, 0, stream>>>(scores);
        // ctx = P * VT^T : A = P bf16 (row byte stride 16384 -> lda 8192 elts)
        gemm_bt_kernel<false, false, true, false>
            <<<dim3(DIM / 128, SEQ / 128), blk, 0, stream>>>(
                (const short*)scores, 8192, VT, SEQ, ctxb, DIM, nullptr, SEQ / 32);
    }
    // out = ctx * W^T + bias  (single launch across all batches)
    gemm_bt_kernel<false, true, false, true>
        <<<dim3(DIM / 128, NB * SEQ / 128), blk, 0, stream>>>(
            ctx, DIM, W, DIM, out, DIM, bias, DIM / 32);
}

// Round 2
// 1301.596 us; speedup vs baseline: 1.1706x; 1.1706x over previous
//
#include <hip/hip_runtime.h>
#include <hip/hip_bf16.h>

typedef __attribute__((ext_vector_type(4))) float f4;
typedef __attribute__((ext_vector_type(4))) short s4;
typedef __attribute__((ext_vector_type(8))) short s8;

#define SEQ 4096
#define DIM 1024
#define NB 8

__device__ inline short f2bf(float f) {
    return __builtin_bit_cast(short, __float2bfloat16(f));
}

__device__ inline void gload_lds16(const void* g, void* l) {
    __builtin_amdgcn_global_load_lds(
        (const __attribute__((address_space(1))) void*)g,
        (__attribute__((address_space(3))) void*)l, 16, 0, 0);
}

// ---------------------------------------------------------------------------
// GEMM: C[M,N] = A[M,K] * B[N,K]^T (+bias). bf16 inputs, fp32 accum.
// 128x128 tile, BK=32, 4 waves (2x2), m97 structure:
//   global_load_lds(16B) staging -> linear LDS, chunk-swizzled global source,
//   swizzled ds_read_b128 frags, 16 MFMA / K-step / wave.
// LDS tile layout: 128 rows x 32 bf16 (64 B/row = 4 chunks of 16 B).
// Swizzle: slot s at row r holds global chunk  s ^ ((r>>1)&3)  (involution).
// ---------------------------------------------------------------------------
template<bool OBF16, bool BIAS>
__global__ __launch_bounds__(256, 2) void gemm_bt(
    const short* __restrict__ A, size_t lda,
    const short* __restrict__ B, size_t ldb,
    void* __restrict__ C, size_t ldc,
    const float* __restrict__ bias, int kIters, int gridN)
{
    __shared__ short lsA[128 * 32];
    __shared__ short lsB[128 * 32];
    const int tid  = threadIdx.x;
    const int lane = tid & 63;
    const int wave = tid >> 6;

    // Bijective XCD-aware swizzle (all our grids are multiples of 8).
    const int nwg = gridDim.x;
    int wg = blockIdx.x;
    wg = (wg & 7) * (nwg >> 3) + (wg >> 3);
    const size_t tm = (size_t)(wg / gridN) * 128;
    const size_t tn = (size_t)(wg % gridN) * 128;

    const int wr = wave >> 1, wc = wave & 1;
    const int fr = lane & 15, kg = lane >> 4;
    const int fxor = (fr >> 1) & 3;           // read-side chunk swizzle

    // Staging geometry: wave w, issue j covers segment (w*2+j) = 16 rows.
    const int sl_row0 = wave * 32 + (lane >> 2);
    const int sl_c    = (lane & 3) ^ ((lane >> 3) & 3);  // inverse-swz source chunk

    f4 acc[4][4];
    #pragma unroll
    for (int m = 0; m < 4; ++m)
        #pragma unroll
        for (int n = 0; n < 4; ++n)
            acc[m][n] = (f4){0.f, 0.f, 0.f, 0.f};

    for (int kt = 0; kt < kIters; ++kt) {
        const size_t k0 = (size_t)kt * 32;
        #pragma unroll
        for (int j = 0; j < 2; ++j) {
            const int row = sl_row0 + j * 16;
            short* lpA = lsA + (wave * 2 + j) * 512 + lane * 8;
            short* lpB = lsB + (wave * 2 + j) * 512 + lane * 8;
            gload_lds16(A + (tm + row) * lda + k0 + sl_c * 8, lpA);
            gload_lds16(B + (tn + row) * ldb + k0 + sl_c * 8, lpB);
        }
        __syncthreads();   // compiler drains vmcnt before s_barrier

        s8 af[4], bf[4];
        #pragma unroll
        for (int m = 0; m < 4; ++m) {
            const int row = wr * 64 + m * 16 + fr;
            af[m] = *(const s8*)(lsA + row * 32 + (kg ^ fxor) * 8);
        }
        #pragma unroll
        for (int n = 0; n < 4; ++n) {
            const int row = wc * 64 + n * 16 + fr;
            bf[n] = *(const s8*)(lsB + row * 32 + (kg ^ fxor) * 8);
        }

        #pragma unroll
        for (int m = 0; m < 4; ++m)
            #pragma unroll
            for (int n = 0; n < 4; ++n)
                acc[m][n] = __builtin_amdgcn_mfma_f32_16x16x32_bf16(af[m], bf[n], acc[m][n], 0, 0, 0);
        __syncthreads();
    }

    // Epilogue. C/D layout: col = lane&15, row = (lane>>4)*4 + i.
    const int cg = lane >> 4;
    const int cl = lane & 15;
    #pragma unroll
    for (int m = 0; m < 4; ++m) {
        #pragma unroll
        for (int n = 0; n < 4; ++n) {
            const size_t grow = tm + wr * 64 + m * 16 + cg * 4;
            const size_t gcol = tn + wc * 64 + n * 16 + cl;
            float bv = 0.f;
            if constexpr (BIAS) bv = bias[gcol];
            #pragma unroll
            for (int i = 0; i < 4; ++i) {
                const float val = acc[m][n][i] + bv;
                if constexpr (OBF16)
                    ((short*)C)[(grow + i) * ldc + gcol] = f2bf(val);
                else
                    ((float*)C)[(grow + i) * ldc + gcol] = val;
            }
        }
    }
}

// fp32 -> bf16, 8 elements/thread.
__global__ __launch_bounds__(256) void conv_bf16(const float* __restrict__ in,
                                                 short* __restrict__ out, int n8)
{
    const int i = blockIdx.x * 256 + threadIdx.x;
    if (i >= n8) return;
    f4 a = ((const f4*)in)[2 * i];
    f4 b = ((const f4*)in)[2 * i + 1];
    s8 w;
    w[0] = f2bf(a[0]); w[1] = f2bf(a[1]); w[2] = f2bf(a[2]); w[3] = f2bf(a[3]);
    w[4] = f2bf(b[0]); w[5] = f2bf(b[1]); w[6] = f2bf(b[2]); w[7] = f2bf(b[3]);
    ((s8*)out)[i] = w;
}

// Row softmax over 4096 fp32 scores (applies 1/sqrt(D) scale), writes bf16 P
// in place over the start of each row (row stays 16384 B apart).
__global__ __launch_bounds__(256) void softmax_rows(float* __restrict__ scores)
{
    const int tid = threadIdx.x;
    float* srow = scores + (size_t)blockIdx.x * SEQ;
    const float SCALE = 0.03125f;  // 1/sqrt(1024)

    f4 v[4];
    float mx = -3.4e38f;
    #pragma unroll
    for (int j = 0; j < 4; ++j) {
        v[j] = *(const f4*)(srow + (size_t)(j * 256 + tid) * 4);
        #pragma unroll
        for (int i = 0; i < 4; ++i) {
            v[j][i] *= SCALE;
            mx = fmaxf(mx, v[j][i]);
        }
    }
    #pragma unroll
    for (int o = 32; o > 0; o >>= 1) mx = fmaxf(mx, __shfl_xor(mx, o));
    __shared__ float red[4];
    if ((tid & 63) == 0) red[tid >> 6] = mx;
    __syncthreads();
    mx = fmaxf(fmaxf(red[0], red[1]), fmaxf(red[2], red[3]));

    float sum = 0.f;
    #pragma unroll
    for (int j = 0; j < 4; ++j)
        #pragma unroll
        for (int i = 0; i < 4; ++i) {
            float e = __expf(v[j][i] - mx);
            v[j][i] = e;
            sum += e;
        }
    #pragma unroll
    for (int o = 32; o > 0; o >>= 1) sum += __shfl_xor(sum, o);
    __syncthreads();
    if ((tid & 63) == 0) red[tid >> 6] = sum;
    __syncthreads();
    const float inv = 1.f / (red[0] + red[1] + red[2] + red[3]);

    short* prow = (short*)srow;
    #pragma unroll
    for (int j = 0; j < 4; ++j) {
        s4 w;
        #pragma unroll
        for (int i = 0; i < 4; ++i) w[i] = f2bf(v[j][i] * inv);
        *(s4*)(prow + (size_t)(j * 256 + tid) * 4) = w;
    }
}

// V[b] fp32 [4096 k][1024 d] -> VT bf16 [1024 d][4096 k], 32x32 tiles.
__global__ __launch_bounds__(256) void transpose_v(const float* __restrict__ V,
                                                   short* __restrict__ VT)
{
    __shared__ float t[32][33];
    const int tid = threadIdx.x;
    const size_t k0 = (size_t)blockIdx.x * 32;
    const size_t d0 = (size_t)blockIdx.y * 32;

    const int r = tid >> 3, c4 = (tid & 7) * 4;
    f4 x = *(const f4*)(V + (k0 + r) * DIM + d0 + c4);
    #pragma unroll
    for (int i = 0; i < 4; ++i) t[r][c4 + i] = x[i];
    __syncthreads();

    const int d = tid >> 3, kk = (tid & 7) * 4;
    s4 w;
    #pragma unroll
    for (int i = 0; i < 4; ++i) w[i] = f2bf(t[kk + i][d]);
    *(s4*)(VT + (d0 + d) * SEQ + k0 + kk) = w;
}

extern "C" void kernel_launch(void* const* d_in, const int* in_sizes, int n_in,
                              void* d_out, int out_size, void* d_ws, size_t ws_size,
                              hipStream_t stream) {
    const float* Q    = (const float*)d_in[0];
    const float* Km   = (const float*)d_in[1];
    const float* V    = (const float*)d_in[2];
    const float* W    = (const float*)d_in[3];
    const float* bias = (const float*)d_in[4];
    float* out = (float*)d_out;

    // ws: ctx bf16 64MB | Qb 8MB | Kb 8MB | VT 8MB | Wb 2MB  (= 90 MB)
    short* ctx = (short*)d_ws;
    short* Qb  = ctx + (size_t)NB * SEQ * DIM;
    short* Kb  = Qb + (size_t)SEQ * DIM;
    short* VT  = Kb + (size_t)SEQ * DIM;
    short* Wb  = VT + (size_t)SEQ * DIM;
    // d_out doubles as per-batch fp32 score scratch (64 MB < 128 MB out).
    float* scores = out;

    const dim3 blk(256);
    conv_bf16<<<DIM * DIM / 2048, blk, 0, stream>>>(W, Wb, DIM * DIM / 8);

    for (int b = 0; b < NB; ++b) {
        const float* Qf = Q  + (size_t)b * SEQ * DIM;
        const float* Kf = Km + (size_t)b * SEQ * DIM;
        const float* Vf = V  + (size_t)b * SEQ * DIM;
        short* ctxb = ctx + (size_t)b * SEQ * DIM;

        conv_bf16<<<SEQ * DIM / 2048, blk, 0, stream>>>(Qf, Qb, SEQ * DIM / 8);
        conv_bf16<<<SEQ * DIM / 2048, blk, 0, stream>>>(Kf, Kb, SEQ * DIM / 8);
        transpose_v<<<dim3(SEQ / 32, DIM / 32), blk, 0, stream>>>(Vf, VT);

        // scores = Qb * Kb^T (raw fp32; scale applied in softmax)
        gemm_bt<false, false><<<dim3(32 * 32), blk, 0, stream>>>(
            Qb, DIM, Kb, DIM, scores, SEQ, nullptr, DIM / 32, 32);

        softmax_rows<<<dim3(SEQ), blk, 0, stream>>>(scores);

        // ctx = P * VT^T : A = P bf16 rows at stride 8192 shorts
        gemm_bt<true, false><<<dim3(32 * 8), blk, 0, stream>>>(
            (const short*)scores, 8192, VT, SEQ, ctxb, DIM, nullptr, SEQ / 32, 8);
    }

    // out = ctx * W^T + bias (all batches, one launch)
    gemm_bt<false, true><<<dim3(NB * 32 * 8), blk, 0, stream>>>(
        ctx, DIM, Wb, DIM, out, DIM, bias, DIM / 32, 8);
}

// Round 6
// 1268.781 us; speedup vs baseline: 1.2009x; 1.0259x over previous
//
#include <hip/hip_runtime.h>
#include <hip/hip_bf16.h>

typedef __attribute__((ext_vector_type(4))) float f4;
typedef __attribute__((ext_vector_type(4))) short s4;
typedef __attribute__((ext_vector_type(8))) short s8;

#define SEQ 4096
#define DIM 1024
#define NB 8

__device__ inline short f2bf(float f) {
    return __builtin_bit_cast(short, __float2bfloat16(f));
}

__device__ inline void gload_lds16(const void* g, void* l) {
    __builtin_amdgcn_global_load_lds(
        (const __attribute__((address_space(1))) void*)g,
        (__attribute__((address_space(3))) void*)l, 16, 0, 0);
}

// ===========================================================================
// gemm256: C[M,N] = A[M,K] * B[N,K]^T. bf16 in, fp32 accum.
// 256x256 tile, BK=32, 8 waves (2Mx4N), safe 2-phase double-buffer
// (__syncthreads drains vmcnt — same proven sync as round-2's gemm_bt).
// LDS buf: A 256x32 bf16 (16KB) + B 16KB; 2 bufs = 64 KB.
// Swizzle: LDS slot s at row r holds global chunk s ^ ((r>>1)&3).
// OUT: 0 = fp32 (+bias if non-null), 2 = bf16.
// ===========================================================================
template<int OUT>
__global__ __launch_bounds__(512, 2) void gemm256(
    const short* __restrict__ A, size_t lda,
    const short* __restrict__ B, size_t ldb,
    void* __restrict__ C, size_t ldc,
    const float* __restrict__ bias, int nt, int gridN)
{
    __shared__ short lds[2 * 16384];
    const int tid  = threadIdx.x;
    const int lane = tid & 63;
    const int wave = tid >> 6;

    const int nwg = gridDim.x;
    int wg = blockIdx.x;
    wg = (wg & 7) * (nwg >> 3) + (wg >> 3);   // bijective (nwg % 8 == 0)
    const size_t tm = (size_t)(wg / gridN) * 256;
    const size_t tn = (size_t)(wg % gridN) * 256;

    // staging: row srow (+128 for second half), chunk schunk of 4x8 shorts
    const int srow   = wave * 16 + (lane >> 2);
    const int schunk = lane & 3;
    const int sc     = schunk ^ ((srow >> 1) & 3);
    const short* pA = A + (tm + srow) * lda + sc * 8;
    const short* pB = B + (tn + srow) * ldb + sc * 8;
    const size_t a128 = (size_t)128 * lda;
    const size_t b128 = (size_t)128 * ldb;
    const int ldst = wave * 512 + lane * 8;

    const int fr = lane & 15, kg = lane >> 4;
    const int ck = kg ^ ((fr >> 1) & 3);
    const int wr = wave >> 2, wc = wave & 3;

    auto STAGE = [&](int t) {
        short* base = lds + (t & 1) * 16384;
        const size_t k0 = (size_t)t * 32;
        gload_lds16(pA + k0,        base + ldst);
        gload_lds16(pA + a128 + k0, base + 4096 + ldst);
        gload_lds16(pB + k0,        base + 8192 + ldst);
        gload_lds16(pB + b128 + k0, base + 12288 + ldst);
    };

    f4 acc[8][4];
    #pragma unroll
    for (int m = 0; m < 8; ++m)
        #pragma unroll
        for (int n = 0; n < 4; ++n)
            acc[m][n] = (f4){0.f, 0.f, 0.f, 0.f};

    STAGE(0);
    __syncthreads();

    for (int t = 0; t < nt; ++t) {
        if (t + 1 < nt) STAGE(t + 1);

        const short* lA = lds + (t & 1) * 16384;
        const short* lB = lA + 8192;
        s8 af[8], bf[4];
        #pragma unroll
        for (int m = 0; m < 8; ++m) {
            const int row = wr * 128 + m * 16 + fr;
            af[m] = *(const s8*)(lA + row * 32 + ck * 8);
        }
        #pragma unroll
        for (int n = 0; n < 4; ++n) {
            const int row = wc * 64 + n * 16 + fr;
            bf[n] = *(const s8*)(lB + row * 32 + ck * 8);
        }
        #pragma unroll
        for (int m = 0; m < 8; ++m)
            #pragma unroll
            for (int n = 0; n < 4; ++n)
                acc[m][n] = __builtin_amdgcn_mfma_f32_16x16x32_bf16(af[m], bf[n], acc[m][n], 0, 0, 0);

        __syncthreads();
    }

    const int cg = lane >> 4, cl = lane & 15;
    #pragma unroll
    for (int m = 0; m < 8; ++m) {
        #pragma unroll
        for (int n = 0; n < 4; ++n) {
            const size_t grow = tm + wr * 128 + m * 16 + cg * 4;
            const size_t gcol = tn + wc * 64 + n * 16 + cl;
            float bv = 0.f;
            if constexpr (OUT == 0) { if (bias) bv = bias[gcol]; }
            #pragma unroll
            for (int i = 0; i < 4; ++i) {
                const float val = acc[m][n][i] + bv;
                if constexpr (OUT == 0)
                    ((float*)C)[(grow + i) * ldc + gcol] = val;
                else
                    ((short*)C)[(grow + i) * ldc + gcol] = f2bf(val);
            }
        }
    }
}

// ===========================================================================
// Round-2 proven 128x128 GEMM (used for PV this round).
// ===========================================================================
template<bool OBF16, bool BIAS>
__global__ __launch_bounds__(256, 2) void gemm_bt(
    const short* __restrict__ A, size_t lda,
    const short* __restrict__ B, size_t ldb,
    void* __restrict__ C, size_t ldc,
    const float* __restrict__ bias, int kIters, int gridN)
{
    __shared__ short lsA[128 * 32];
    __shared__ short lsB[128 * 32];
    const int tid  = threadIdx.x;
    const int lane = tid & 63;
    const int wave = tid >> 6;

    const int nwg = gridDim.x;
    int wg = blockIdx.x;
    wg = (wg & 7) * (nwg >> 3) + (wg >> 3);
    const size_t tm = (size_t)(wg / gridN) * 128;
    const size_t tn = (size_t)(wg % gridN) * 128;

    const int wr = wave >> 1, wc = wave & 1;
    const int fr = lane & 15, kg = lane >> 4;
    const int fxor = (fr >> 1) & 3;
    const int sl_row0 = wave * 32 + (lane >> 2);
    const int sl_c    = (lane & 3) ^ ((lane >> 3) & 3);

    f4 acc[4][4];
    #pragma unroll
    for (int m = 0; m < 4; ++m)
        #pragma unroll
        for (int n = 0; n < 4; ++n)
            acc[m][n] = (f4){0.f, 0.f, 0.f, 0.f};

    for (int kt = 0; kt < kIters; ++kt) {
        const size_t k0 = (size_t)kt * 32;
        #pragma unroll
        for (int j = 0; j < 2; ++j) {
            const int row = sl_row0 + j * 16;
            gload_lds16(A + (tm + row) * lda + k0 + sl_c * 8, lsA + (wave * 2 + j) * 512 + lane * 8);
            gload_lds16(B + (tn + row) * ldb + k0 + sl_c * 8, lsB + (wave * 2 + j) * 512 + lane * 8);
        }
        __syncthreads();

        s8 af[4], bf[4];
        #pragma unroll
        for (int m = 0; m < 4; ++m)
            af[m] = *(const s8*)(lsA + (wr * 64 + m * 16 + fr) * 32 + (kg ^ fxor) * 8);
        #pragma unroll
        for (int n = 0; n < 4; ++n)
            bf[n] = *(const s8*)(lsB + (wc * 64 + n * 16 + fr) * 32 + (kg ^ fxor) * 8);

        #pragma unroll
        for (int m = 0; m < 4; ++m)
            #pragma unroll
            for (int n = 0; n < 4; ++n)
                acc[m][n] = __builtin_amdgcn_mfma_f32_16x16x32_bf16(af[m], bf[n], acc[m][n], 0, 0, 0);
        __syncthreads();
    }

    const int cg = lane >> 4, cl = lane & 15;
    #pragma unroll
    for (int m = 0; m < 4; ++m) {
        #pragma unroll
        for (int n = 0; n < 4; ++n) {
            const size_t grow = tm + wr * 64 + m * 16 + cg * 4;
            const size_t gcol = tn + wc * 64 + n * 16 + cl;
            float bv = 0.f;
            if constexpr (BIAS) bv = bias[gcol];
            #pragma unroll
            for (int i = 0; i < 4; ++i) {
                const float val = acc[m][n][i] + bv;
                if constexpr (OBF16)
                    ((short*)C)[(grow + i) * ldc + gcol] = f2bf(val);
                else
                    ((float*)C)[(grow + i) * ldc + gcol] = val;
            }
        }
    }
}

// fp32 -> bf16, 8 elements/thread (scale 1.0 everywhere this round).
__global__ __launch_bounds__(256) void conv_bf16(const float* __restrict__ in,
                                                 short* __restrict__ out, int n8)
{
    const int i = blockIdx.x * 256 + threadIdx.x;
    if (i >= n8) return;
    f4 a = ((const f4*)in)[2 * i];
    f4 b = ((const f4*)in)[2 * i + 1];
    s8 w;
    w[0] = f2bf(a[0]); w[1] = f2bf(a[1]); w[2] = f2bf(a[2]); w[3] = f2bf(a[3]);
    w[4] = f2bf(b[0]); w[5] = f2bf(b[1]); w[6] = f2bf(b[2]); w[7] = f2bf(b[3]);
    ((s8*)out)[i] = w;
}

// Round-2 proven fp32 softmax: applies scale, writes bf16 P in place (lda 8192).
__global__ __launch_bounds__(256) void softmax_rows(float* __restrict__ scores)
{
    const int tid = threadIdx.x;
    float* srow = scores + (size_t)blockIdx.x * SEQ;
    const float SCALE = 0.03125f;

    f4 v[4];
    float mx = -3.4e38f;
    #pragma unroll
    for (int j = 0; j < 4; ++j) {
        v[j] = *(const f4*)(srow + (size_t)(j * 256 + tid) * 4);
        #pragma unroll
        for (int i = 0; i < 4; ++i) {
            v[j][i] *= SCALE;
            mx = fmaxf(mx, v[j][i]);
        }
    }
    #pragma unroll
    for (int o = 32; o > 0; o >>= 1) mx = fmaxf(mx, __shfl_xor(mx, o));
    __shared__ float red[4];
    if ((tid & 63) == 0) red[tid >> 6] = mx;
    __syncthreads();
    mx = fmaxf(fmaxf(red[0], red[1]), fmaxf(red[2], red[3]));

    float sum = 0.f;
    #pragma unroll
    for (int j = 0; j < 4; ++j)
        #pragma unroll
        for (int i = 0; i < 4; ++i) {
            const float e = __expf(v[j][i] - mx);
            v[j][i] = e;
            sum += e;
        }
    #pragma unroll
    for (int o = 32; o > 0; o >>= 1) sum += __shfl_xor(sum, o);
    __syncthreads();
    if ((tid & 63) == 0) red[tid >> 6] = sum;
    __syncthreads();
    const float inv = 1.f / (red[0] + red[1] + red[2] + red[3]);

    short* prow = (short*)srow;
    #pragma unroll
    for (int j = 0; j < 4; ++j) {
        s4 w;
        #pragma unroll
        for (int i = 0; i < 4; ++i) w[i] = f2bf(v[j][i] * inv);
        *(s4*)(prow + (size_t)(j * 256 + tid) * 4) = w;
    }
}

// V fp32 [4096 k][1024 d] -> VT bf16 [1024 d][4096 k], 32x32 tiles.
__global__ __launch_bounds__(256) void transpose_v(const float* __restrict__ V,
                                                   short* __restrict__ VT)
{
    __shared__ float t[32][33];
    const int tid = threadIdx.x;
    const size_t k0 = (size_t)blockIdx.x * 32;
    const size_t d0 = (size_t)blockIdx.y * 32;

    const int r = tid >> 3, c4 = (tid & 7) * 4;
    f4 x = *(const f4*)(V + (k0 + r) * DIM + d0 + c4);
    #pragma unroll
    for (int i = 0; i < 4; ++i) t[r][c4 + i] = x[i];
    __syncthreads();

    const int d = tid >> 3, kk = (tid & 7) * 4;
    s4 w;
    #pragma unroll
    for (int i = 0; i < 4; ++i) w[i] = f2bf(t[kk + i][d]);
    *(s4*)(VT + (d0 + d) * SEQ + k0 + kk) = w;
}

extern "C" void kernel_launch(void* const* d_in, const int* in_sizes, int n_in,
                              void* d_out, int out_size, void* d_ws, size_t ws_size,
                              hipStream_t stream) {
    const float* Q    = (const float*)d_in[0];
    const float* Km   = (const float*)d_in[1];
    const float* V    = (const float*)d_in[2];
    const float* W    = (const float*)d_in[3];
    const float* bias = (const float*)d_in[4];
    float* out = (float*)d_out;

    // Round-2 ws layout: ctx bf16 64MB | Qb 8MB | Kb 8MB | VT 8MB | Wb 2MB
    short* ctx = (short*)d_ws;
    short* Qb  = ctx + (size_t)NB * SEQ * DIM;
    short* Kb  = Qb + (size_t)SEQ * DIM;
    short* VT  = Kb + (size_t)SEQ * DIM;
    short* Wb  = VT + (size_t)SEQ * DIM;
    float* scores = out;   // d_out doubles as per-batch fp32 score scratch

    const dim3 blk256(256), blk512(512);
    conv_bf16<<<DIM * DIM / 2048, blk256, 0, stream>>>(W, Wb, DIM * DIM / 8);

    for (int b = 0; b < NB; ++b) {
        const float* Qf = Q  + (size_t)b * SEQ * DIM;
        const float* Kf = Km + (size_t)b * SEQ * DIM;
        const float* Vf = V  + (size_t)b * SEQ * DIM;
        short* ctxb = ctx + (size_t)b * SEQ * DIM;

        conv_bf16<<<SEQ * DIM / 2048, blk256, 0, stream>>>(Qf, Qb, SEQ * DIM / 8);
        conv_bf16<<<SEQ * DIM / 2048, blk256, 0, stream>>>(Kf, Kb, SEQ * DIM / 8);
        transpose_v<<<dim3(SEQ / 32, DIM / 32), blk256, 0, stream>>>(Vf, VT);

        // [ONLY CHANGE vs round 2] scores = Qb * Kb^T via gemm256 (fp32 out)
        gemm256<0><<<dim3(256, 1), blk512, 0, stream>>>(
            Qb, DIM, Kb, DIM, scores, SEQ, nullptr, DIM / 32, 16);

        softmax_rows<<<dim3(SEQ), blk256, 0, stream>>>(scores);

        // PV exactly as round 2: P bf16 packed at lda 8192
        gemm_bt<true, false><<<dim3(32 * 8), blk256, 0, stream>>>(
            (const short*)scores, 8192, VT, SEQ, ctxb, DIM, nullptr, SEQ / 32, 8);
    }

    // [CHANGE vs round 2] proj via gemm256 (fp32 + bias)
    gemm256<0><<<dim3(512, 1), blk512, 0, stream>>>(
        ctx, DIM, Wb, DIM, out, DIM, bias, DIM / 32, 4);
}

// Round 7
// 1261.002 us; speedup vs baseline: 1.2083x; 1.0062x over previous
//
#include <hip/hip_runtime.h>
#include <hip/hip_bf16.h>

typedef __attribute__((ext_vector_type(4))) float f4;
typedef __attribute__((ext_vector_type(4))) short s4;
typedef __attribute__((ext_vector_type(8))) short s8;

#define SEQ 4096
#define DIM 1024
#define NB 8

__device__ inline short f2bf(float f) {
    return __builtin_bit_cast(short, __float2bfloat16(f));
}

__device__ inline void gload_lds16(const void* g, void* l) {
    __builtin_amdgcn_global_load_lds(
        (const __attribute__((address_space(1))) void*)g,
        (__attribute__((address_space(3))) void*)l, 16, 0, 0);
}

// ===========================================================================
// gemm256: C[M,N] = A[M,K] * B[N,K]^T. bf16 in, fp32 accum.
// 256x256 tile, BK=32, 8 waves (2Mx4N). Schedule: 4-deep LDS ring (128 KB),
// raw s_barrier + COUNTED vmcnt(8) -> 3 tiles of prefetch stay in flight
// across barriers (T3+T4; never drains to 0 in steady state).
// Core formulas (staging/swizzle/frag/epilogue) validated in round 6.
// Swizzle: LDS slot s at row r holds global chunk s ^ ((r>>1)&3).
// OUT: 0 = fp32 (+bias if non-null), 2 = bf16.
// ===========================================================================
template<int OUT>
__global__ __launch_bounds__(512, 2) void gemm256(
    const short* __restrict__ A, size_t lda,
    const short* __restrict__ B, size_t ldb,
    void* __restrict__ C, size_t ldc,
    const float* __restrict__ bias, int nt, int gridN)
{
    __shared__ short lds[4 * 16384];   // 4 bufs x {A 8192, B 8192} shorts
    const int tid  = threadIdx.x;
    const int lane = tid & 63;
    const int wave = tid >> 6;

    const int nwg = gridDim.x;
    int wg = blockIdx.x;
    wg = (wg & 7) * (nwg >> 3) + (wg >> 3);   // bijective (nwg % 8 == 0)
    const size_t tm = (size_t)(wg / gridN) * 256;
    const size_t tn = (size_t)(wg % gridN) * 256;

    // staging: row srow (+128 for second half), chunk sc of 8 shorts
    const int srow   = wave * 16 + (lane >> 2);
    const int schunk = lane & 3;
    const int sc     = schunk ^ ((srow >> 1) & 3);
    const short* pA = A + (tm + srow) * lda + sc * 8;
    const short* pB = B + (tn + srow) * ldb + sc * 8;
    const size_t a128 = (size_t)128 * lda;
    const size_t b128 = (size_t)128 * ldb;
    const int ldst = wave * 512 + lane * 8;

    const int fr = lane & 15, kg = lane >> 4;
    const int ck = kg ^ ((fr >> 1) & 3);
    const int wr = wave >> 2, wc = wave & 3;

    auto STAGE = [&](int t) {
        short* base = lds + (t & 3) * 16384;
        const size_t k0 = (size_t)t * 32;
        gload_lds16(pA + k0,        base + ldst);
        gload_lds16(pA + a128 + k0, base + 4096 + ldst);
        gload_lds16(pB + k0,        base + 8192 + ldst);
        gload_lds16(pB + b128 + k0, base + 12288 + ldst);
    };

    f4 acc[8][4];
    #pragma unroll
    for (int m = 0; m < 8; ++m)
        #pragma unroll
        for (int n = 0; n < 4; ++n)
            acc[m][n] = (f4){0.f, 0.f, 0.f, 0.f};

    STAGE(0); STAGE(1); STAGE(2);               // 12 loads in flight
    asm volatile("s_waitcnt vmcnt(8)" ::: "memory");   // tile 0 landed
    __builtin_amdgcn_s_barrier();
    __builtin_amdgcn_sched_barrier(0);

    for (int t = 0; t < nt; ++t) {
        if (t + 3 < nt) STAGE(t + 3);   // writes buf[(t-1)&3]; reads of it
                                        // finished before end-of-(t-1) barrier

        const short* lA = lds + (t & 3) * 16384;
        const short* lB = lA + 8192;
        s8 af[8], bf[4];
        #pragma unroll
        for (int m = 0; m < 8; ++m) {
            const int row = wr * 128 + m * 16 + fr;
            af[m] = *(const s8*)(lA + row * 32 + ck * 8);
        }
        #pragma unroll
        for (int n = 0; n < 4; ++n) {
            const int row = wc * 64 + n * 16 + fr;
            bf[n] = *(const s8*)(lB + row * 32 + ck * 8);
        }
        #pragma unroll
        for (int m = 0; m < 8; ++m)
            #pragma unroll
            for (int n = 0; n < 4; ++n)
                acc[m][n] = __builtin_amdgcn_mfma_f32_16x16x32_bf16(af[m], bf[n], acc[m][n], 0, 0, 0);

        // tile t+1 must be landed before next iter; keep rest in flight
        if (t + 4 <= nt) {
            asm volatile("s_waitcnt vmcnt(8)" ::: "memory");
        } else if (t + 3 == nt) {
            asm volatile("s_waitcnt vmcnt(4)" ::: "memory");
        } else if (t + 2 == nt) {
            asm volatile("s_waitcnt vmcnt(0)" ::: "memory");
        }
        if (t + 1 < nt) {
            __builtin_amdgcn_s_barrier();
            __builtin_amdgcn_sched_barrier(0);
        }
    }

    const int cg = lane >> 4, cl = lane & 15;
    #pragma unroll
    for (int m = 0; m < 8; ++m) {
        #pragma unroll
        for (int n = 0; n < 4; ++n) {
            const size_t grow = tm + wr * 128 + m * 16 + cg * 4;
            const size_t gcol = tn + wc * 64 + n * 16 + cl;
            float bv = 0.f;
            if constexpr (OUT == 0) { if (bias) bv = bias[gcol]; }
            #pragma unroll
            for (int i = 0; i < 4; ++i) {
                const float val = acc[m][n][i] + bv;
                if constexpr (OUT == 0)
                    ((float*)C)[(grow + i) * ldc + gcol] = val;
                else
                    ((short*)C)[(grow + i) * ldc + gcol] = f2bf(val);
            }
        }
    }
}

// ===========================================================================
// Round-2 proven 128x128 GEMM (PV).
// ===========================================================================
template<bool OBF16, bool BIAS>
__global__ __launch_bounds__(256, 2) void gemm_bt(
    const short* __restrict__ A, size_t lda,
    const short* __restrict__ B, size_t ldb,
    void* __restrict__ C, size_t ldc,
    const float* __restrict__ bias, int kIters, int gridN)
{
    __shared__ short lsA[128 * 32];
    __shared__ short lsB[128 * 32];
    const int tid  = threadIdx.x;
    const int lane = tid & 63;
    const int wave = tid >> 6;

    const int nwg = gridDim.x;
    int wg = blockIdx.x;
    wg = (wg & 7) * (nwg >> 3) + (wg >> 3);
    const size_t tm = (size_t)(wg / gridN) * 128;
    const size_t tn = (size_t)(wg % gridN) * 128;

    const int wr = wave >> 1, wc = wave & 1;
    const int fr = lane & 15, kg = lane >> 4;
    const int fxor = (fr >> 1) & 3;
    const int sl_row0 = wave * 32 + (lane >> 2);
    const int sl_c    = (lane & 3) ^ ((lane >> 3) & 3);

    f4 acc[4][4];
    #pragma unroll
    for (int m = 0; m < 4; ++m)
        #pragma unroll
        for (int n = 0; n < 4; ++n)
            acc[m][n] = (f4){0.f, 0.f, 0.f, 0.f};

    for (int kt = 0; kt < kIters; ++kt) {
        const size_t k0 = (size_t)kt * 32;
        #pragma unroll
        for (int j = 0; j < 2; ++j) {
            const int row = sl_row0 + j * 16;
            gload_lds16(A + (tm + row) * lda + k0 + sl_c * 8, lsA + (wave * 2 + j) * 512 + lane * 8);
            gload_lds16(B + (tn + row) * ldb + k0 + sl_c * 8, lsB + (wave * 2 + j) * 512 + lane * 8);
        }
        __syncthreads();

        s8 af[4], bf[4];
        #pragma unroll
        for (int m = 0; m < 4; ++m)
            af[m] = *(const s8*)(lsA + (wr * 64 + m * 16 + fr) * 32 + (kg ^ fxor) * 8);
        #pragma unroll
        for (int n = 0; n < 4; ++n)
            bf[n] = *(const s8*)(lsB + (wc * 64 + n * 16 + fr) * 32 + (kg ^ fxor) * 8);

        #pragma unroll
        for (int m = 0; m < 4; ++m)
            #pragma unroll
            for (int n = 0; n < 4; ++n)
                acc[m][n] = __builtin_amdgcn_mfma_f32_16x16x32_bf16(af[m], bf[n], acc[m][n], 0, 0, 0);
        __syncthreads();
    }

    const int cg = lane >> 4, cl = lane & 15;
    #pragma unroll
    for (int m = 0; m < 4; ++m) {
        #pragma unroll
        for (int n = 0; n < 4; ++n) {
            const size_t grow = tm + wr * 64 + m * 16 + cg * 4;
            const size_t gcol = tn + wc * 64 + n * 16 + cl;
            float bv = 0.f;
            if constexpr (BIAS) bv = bias[gcol];
            #pragma unroll
            for (int i = 0; i < 4; ++i) {
                const float val = acc[m][n][i] + bv;
                if constexpr (OBF16)
                    ((short*)C)[(grow + i) * ldc + gcol] = f2bf(val);
                else
                    ((float*)C)[(grow + i) * ldc + gcol] = val;
            }
        }
    }
}

// fp32 -> bf16, 8 elements/thread.
__global__ __launch_bounds__(256) void conv_bf16(const float* __restrict__ in,
                                                 short* __restrict__ out, int n8)
{
    const int i = blockIdx.x * 256 + threadIdx.x;
    if (i >= n8) return;
    f4 a = ((const f4*)in)[2 * i];
    f4 b = ((const f4*)in)[2 * i + 1];
    s8 w;
    w[0] = f2bf(a[0]); w[1] = f2bf(a[1]); w[2] = f2bf(a[2]); w[3] = f2bf(a[3]);
    w[4] = f2bf(b[0]); w[5] = f2bf(b[1]); w[6] = f2bf(b[2]); w[7] = f2bf(b[3]);
    ((s8*)out)[i] = w;
}

// Proven fp32 softmax: applies scale, writes bf16 P in place (lda 8192).
__global__ __launch_bounds__(256) void softmax_rows(float* __restrict__ scores)
{
    const int tid = threadIdx.x;
    float* srow = scores + (size_t)blockIdx.x * SEQ;
    const float SCALE = 0.03125f;

    f4 v[4];
    float mx = -3.4e38f;
    #pragma unroll
    for (int j = 0; j < 4; ++j) {
        v[j] = *(const f4*)(srow + (size_t)(j * 256 + tid) * 4);
        #pragma unroll
        for (int i = 0; i < 4; ++i) {
            v[j][i] *= SCALE;
            mx = fmaxf(mx, v[j][i]);
        }
    }
    #pragma unroll
    for (int o = 32; o > 0; o >>= 1) mx = fmaxf(mx, __shfl_xor(mx, o));
    __shared__ float red[4];
    if ((tid & 63) == 0) red[tid >> 6] = mx;
    __syncthreads();
    mx = fmaxf(fmaxf(red[0], red[1]), fmaxf(red[2], red[3]));

    float sum = 0.f;
    #pragma unroll
    for (int j = 0; j < 4; ++j)
        #pragma unroll
        for (int i = 0; i < 4; ++i) {
            const float e = __expf(v[j][i] - mx);
            v[j][i] = e;
            sum += e;
        }
    #pragma unroll
    for (int o = 32; o > 0; o >>= 1) sum += __shfl_xor(sum, o);
    __syncthreads();
    if ((tid & 63) == 0) red[tid >> 6] = sum;
    __syncthreads();
    const float inv = 1.f / (red[0] + red[1] + red[2] + red[3]);

    short* prow = (short*)srow;
    #pragma unroll
    for (int j = 0; j < 4; ++j) {
        s4 w;
        #pragma unroll
        for (int i = 0; i < 4; ++i) w[i] = f2bf(v[j][i] * inv);
        *(s4*)(prow + (size_t)(j * 256 + tid) * 4) = w;
    }
}

// V fp32 [4096 k][1024 d] -> VT bf16 [1024 d][4096 k], 32x32 tiles.
__global__ __launch_bounds__(256) void transpose_v(const float* __restrict__ V,
                                                   short* __restrict__ VT)
{
    __shared__ float t[32][33];
    const int tid = threadIdx.x;
    const size_t k0 = (size_t)blockIdx.x * 32;
    const size_t d0 = (size_t)blockIdx.y * 32;

    const int r = tid >> 3, c4 = (tid & 7) * 4;
    f4 x = *(const f4*)(V + (k0 + r) * DIM + d0 + c4);
    #pragma unroll
    for (int i = 0; i < 4; ++i) t[r][c4 + i] = x[i];
    __syncthreads();

    const int d = tid >> 3, kk = (tid & 7) * 4;
    s4 w;
    #pragma unroll
    for (int i = 0; i < 4; ++i) w[i] = f2bf(t[kk + i][d]);
    *(s4*)(VT + (d0 + d) * SEQ + k0 + kk) = w;
}

extern "C" void kernel_launch(void* const* d_in, const int* in_sizes, int n_in,
                              void* d_out, int out_size, void* d_ws, size_t ws_size,
                              hipStream_t stream) {
    const float* Q    = (const float*)d_in[0];
    const float* Km   = (const float*)d_in[1];
    const float* V    = (const float*)d_in[2];
    const float* W    = (const float*)d_in[3];
    const float* bias = (const float*)d_in[4];
    float* out = (float*)d_out;

    // ws: ctx bf16 64MB | Qb 8MB | Kb 8MB | VT 8MB | Wb 2MB
    short* ctx = (short*)d_ws;
    short* Qb  = ctx + (size_t)NB * SEQ * DIM;
    short* Kb  = Qb + (size_t)SEQ * DIM;
    short* VT  = Kb + (size_t)SEQ * DIM;
    short* Wb  = VT + (size_t)SEQ * DIM;
    float* scores = out;   // d_out doubles as per-batch fp32 score scratch

    const dim3 blk256(256), blk512(512);
    conv_bf16<<<DIM * DIM / 2048, blk256, 0, stream>>>(W, Wb, DIM * DIM / 8);

    for (int b = 0; b < NB; ++b) {
        const float* Qf = Q  + (size_t)b * SEQ * DIM;
        const float* Kf = Km + (size_t)b * SEQ * DIM;
        const float* Vf = V  + (size_t)b * SEQ * DIM;
        short* ctxb = ctx + (size_t)b * SEQ * DIM;

        conv_bf16<<<SEQ * DIM / 2048, blk256, 0, stream>>>(Qf, Qb, SEQ * DIM / 8);
        conv_bf16<<<SEQ * DIM / 2048, blk256, 0, stream>>>(Kf, Kb, SEQ * DIM / 8);
        transpose_v<<<dim3(SEQ / 32, DIM / 32), blk256, 0, stream>>>(Vf, VT);

        // scores = Qb * Kb^T (fp32 out; scale applied in softmax)
        gemm256<0><<<dim3(256, 1), blk512, 0, stream>>>(
            Qb, DIM, Kb, DIM, scores, SEQ, nullptr, DIM / 32, 16);

        softmax_rows<<<dim3(SEQ), blk256, 0, stream>>>(scores);

        // PV: P bf16 packed at lda 8192
        gemm_bt<true, false><<<dim3(32 * 8), blk256, 0, stream>>>(
            (const short*)scores, 8192, VT, SEQ, ctxb, DIM, nullptr, SEQ / 32, 8);
    }

    // proj: out = ctx * W^T + bias
    gemm256<0><<<dim3(512, 1), blk512, 0, stream>>>(
        ctx, DIM, Wb, DIM, out, DIM, bias, DIM / 32, 4);
}

// Round 9
// 1242.327 us; speedup vs baseline: 1.2264x; 1.0150x over previous
//
#include <hip/hip_runtime.h>
#include <hip/hip_bf16.h>

typedef __attribute__((ext_vector_type(4))) float f4;
typedef __attribute__((ext_vector_type(4))) short s4;
typedef __attribute__((ext_vector_type(8))) short s8;

#define SEQ 4096
#define DIM 1024
#define NB 8

__device__ inline short f2bf(float f) {
    return __builtin_bit_cast(short, __float2bfloat16(f));
}

__device__ inline void gload_lds16(const void* g, void* l) {
    __builtin_amdgcn_global_load_lds(
        (const __attribute__((address_space(1))) void*)g,
        (__attribute__((address_space(3))) void*)l, 16, 0, 0);
}

// ===========================================================================
// gemm256: C[M,N] = A[M,K] * B[N,K]^T. bf16 in, fp32 accum.
// 256x256 tile, BK=32, 8 waves (2Mx4N). 4-deep LDS ring (128 KB),
// raw s_barrier + COUNTED vmcnt(8): 3 tiles of prefetch stay in flight
// across barriers. Core + ring validated rounds 6-7 (absmax 9.77e-4).
// This round: + T5 s_setprio around the MFMA cluster (hint only).
// Swizzle: LDS slot s at row r holds global chunk s ^ ((r>>1)&3).
// OUT: 0 = fp32 (+bias if non-null).
// ===========================================================================
template<int OUT>
__global__ __launch_bounds__(512, 2) void gemm256(
    const short* __restrict__ A, size_t lda,
    const short* __restrict__ B, size_t ldb,
    void* __restrict__ C, size_t ldc,
    const float* __restrict__ bias, int nt, int gridN)
{
    __shared__ short lds[4 * 16384];   // 4 bufs x {A 8192, B 8192} shorts
    const int tid  = threadIdx.x;
    const int lane = tid & 63;
    const int wave = tid >> 6;

    const int nwg = gridDim.x;
    int wg = blockIdx.x;
    wg = (wg & 7) * (nwg >> 3) + (wg >> 3);   // bijective (nwg % 8 == 0)
    const size_t tm = (size_t)(wg / gridN) * 256;
    const size_t tn = (size_t)(wg % gridN) * 256;

    const int srow   = wave * 16 + (lane >> 2);
    const int schunk = lane & 3;
    const int sc     = schunk ^ ((srow >> 1) & 3);
    const short* pA = A + (tm + srow) * lda + sc * 8;
    const short* pB = B + (tn + srow) * ldb + sc * 8;
    const size_t a128 = (size_t)128 * lda;
    const size_t b128 = (size_t)128 * ldb;
    const int ldst = wave * 512 + lane * 8;

    const int fr = lane & 15, kg = lane >> 4;
    const int ck = kg ^ ((fr >> 1) & 3);
    const int wr = wave >> 2, wc = wave & 3;

    auto STAGE = [&](int t) {
        short* base = lds + (t & 3) * 16384;
        const size_t k0 = (size_t)t * 32;
        gload_lds16(pA + k0,        base + ldst);
        gload_lds16(pA + a128 + k0, base + 4096 + ldst);
        gload_lds16(pB + k0,        base + 8192 + ldst);
        gload_lds16(pB + b128 + k0, base + 12288 + ldst);
    };

    f4 acc[8][4];
    #pragma unroll
    for (int m = 0; m < 8; ++m)
        #pragma unroll
        for (int n = 0; n < 4; ++n)
            acc[m][n] = (f4){0.f, 0.f, 0.f, 0.f};

    STAGE(0); STAGE(1); STAGE(2);               // 12 loads in flight
    asm volatile("s_waitcnt vmcnt(8)" ::: "memory");   // tile 0 landed
    __builtin_amdgcn_s_barrier();
    __builtin_amdgcn_sched_barrier(0);

    for (int t = 0; t < nt; ++t) {
        if (t + 3 < nt) STAGE(t + 3);   // writes buf[(t-1)&3]; its reads
                                        // completed before last barrier

        const short* lA = lds + (t & 3) * 16384;
        const short* lB = lA + 8192;
        s8 af[8], bf[4];
        #pragma unroll
        for (int m = 0; m < 8; ++m) {
            const int row = wr * 128 + m * 16 + fr;
            af[m] = *(const s8*)(lA + row * 32 + ck * 8);
        }
        #pragma unroll
        for (int n = 0; n < 4; ++n) {
            const int row = wc * 64 + n * 16 + fr;
            bf[n] = *(const s8*)(lB + row * 32 + ck * 8);
        }
        __builtin_amdgcn_s_setprio(1);
        #pragma unroll
        for (int m = 0; m < 8; ++m)
            #pragma unroll
            for (int n = 0; n < 4; ++n)
                acc[m][n] = __builtin_amdgcn_mfma_f32_16x16x32_bf16(af[m], bf[n], acc[m][n], 0, 0, 0);
        __builtin_amdgcn_s_setprio(0);

        if (t + 4 <= nt) {
            asm volatile("s_waitcnt vmcnt(8)" ::: "memory");
        } else if (t + 3 == nt) {
            asm volatile("s_waitcnt vmcnt(4)" ::: "memory");
        } else if (t + 2 == nt) {
            asm volatile("s_waitcnt vmcnt(0)" ::: "memory");
        }
        if (t + 1 < nt) {
            __builtin_amdgcn_s_barrier();
            __builtin_amdgcn_sched_barrier(0);
        }
    }

    const int cg = lane >> 4, cl = lane & 15;
    #pragma unroll
    for (int m = 0; m < 8; ++m) {
        #pragma unroll
        for (int n = 0; n < 4; ++n) {
            const size_t grow = tm + wr * 128 + m * 16 + cg * 4;
            const size_t gcol = tn + wc * 64 + n * 16 + cl;
            float bv = 0.f;
            if constexpr (OUT == 0) { if (bias) bv = bias[gcol]; }
            #pragma unroll
            for (int i = 0; i < 4; ++i) {
                const float val = acc[m][n][i] + bv;
                ((float*)C)[(grow + i) * ldc + gcol] = val;
            }
        }
    }
}

// ===========================================================================
// Round-2 proven 128x128 GEMM (PV) — unchanged.
// ===========================================================================
template<bool OBF16, bool BIAS>
__global__ __launch_bounds__(256, 2) void gemm_bt(
    const short* __restrict__ A, size_t lda,
    const short* __restrict__ B, size_t ldb,
    void* __restrict__ C, size_t ldc,
    const float* __restrict__ bias, int kIters, int gridN)
{
    __shared__ short lsA[128 * 32];
    __shared__ short lsB[128 * 32];
    const int tid  = threadIdx.x;
    const int lane = tid & 63;
    const int wave = tid >> 6;

    const int nwg = gridDim.x;
    int wg = blockIdx.x;
    wg = (wg & 7) * (nwg >> 3) + (wg >> 3);
    const size_t tm = (size_t)(wg / gridN) * 128;
    const size_t tn = (size_t)(wg % gridN) * 128;

    const int wr = wave >> 1, wc = wave & 1;
    const int fr = lane & 15, kg = lane >> 4;
    const int fxor = (fr >> 1) & 3;
    const int sl_row0 = wave * 32 + (lane >> 2);
    const int sl_c    = (lane & 3) ^ ((lane >> 3) & 3);

    f4 acc[4][4];
    #pragma unroll
    for (int m = 0; m < 4; ++m)
        #pragma unroll
        for (int n = 0; n < 4; ++n)
            acc[m][n] = (f4){0.f, 0.f, 0.f, 0.f};

    for (int kt = 0; kt < kIters; ++kt) {
        const size_t k0 = (size_t)kt * 32;
        #pragma unroll
        for (int j = 0; j < 2; ++j) {
            const int row = sl_row0 + j * 16;
            gload_lds16(A + (tm + row) * lda + k0 + sl_c * 8, lsA + (wave * 2 + j) * 512 + lane * 8);
            gload_lds16(B + (tn + row) * ldb + k0 + sl_c * 8, lsB + (wave * 2 + j) * 512 + lane * 8);
        }
        __syncthreads();

        s8 af[4], bf[4];
        #pragma unroll
        for (int m = 0; m < 4; ++m)
            af[m] = *(const s8*)(lsA + (wr * 64 + m * 16 + fr) * 32 + (kg ^ fxor) * 8);
        #pragma unroll
        for (int n = 0; n < 4; ++n)
            bf[n] = *(const s8*)(lsB + (wc * 64 + n * 16 + fr) * 32 + (kg ^ fxor) * 8);

        #pragma unroll
        for (int m = 0; m < 4; ++m)
            #pragma unroll
            for (int n = 0; n < 4; ++n)
                acc[m][n] = __builtin_amdgcn_mfma_f32_16x16x32_bf16(af[m], bf[n], acc[m][n], 0, 0, 0);
        __syncthreads();
    }

    const int cg = lane >> 4, cl = lane & 15;
    #pragma unroll
    for (int m = 0; m < 4; ++m) {
        #pragma unroll
        for (int n = 0; n < 4; ++n) {
            const size_t grow = tm + wr * 64 + m * 16 + cg * 4;
            const size_t gcol = tn + wc * 64 + n * 16 + cl;
            float bv = 0.f;
            if constexpr (BIAS) bv = bias[gcol];
            #pragma unroll
            for (int i = 0; i < 4; ++i) {
                const float val = acc[m][n][i] + bv;
                if constexpr (OBF16)
                    ((short*)C)[(grow + i) * ldc + gcol] = f2bf(val);
                else
                    ((float*)C)[(grow + i) * ldc + gcol] = val;
            }
        }
    }
}

// fp32 -> bf16, 8 elements/thread (W only).
__global__ __launch_bounds__(256) void conv_bf16(const float* __restrict__ in,
                                                 short* __restrict__ out, int n8)
{
    const int i = blockIdx.x * 256 + threadIdx.x;
    if (i >= n8) return;
    f4 a = ((const f4*)in)[2 * i];
    f4 b = ((const f4*)in)[2 * i + 1];
    s8 w;
    w[0] = f2bf(a[0]); w[1] = f2bf(a[1]); w[2] = f2bf(a[2]); w[3] = f2bf(a[3]);
    w[4] = f2bf(b[0]); w[5] = f2bf(b[1]); w[6] = f2bf(b[2]); w[7] = f2bf(b[3]);
    ((s8*)out)[i] = w;
}

// ===========================================================================
// prep_batch: one launch per batch doing Q-conv, K-conv, V-transpose.
// blocks [0,2048): Q conv (proven conv body, 8 elts/thread)
// blocks [2048,4096): K conv
// blocks [4096,8192): V transpose (proven transpose_v body; kt = b2%128, dt = b2/128)
// ===========================================================================
__global__ __launch_bounds__(256) void prep_batch(
    const float* __restrict__ Qf, const float* __restrict__ Kf,
    const float* __restrict__ Vf,
    short* __restrict__ Qb, short* __restrict__ Kb, short* __restrict__ VT)
{
    const int tid = threadIdx.x;
    const int blk = blockIdx.x;

    if (blk < 4096) {
        const float* in = (blk < 2048) ? Qf : Kf;
        short* out      = (blk < 2048) ? Qb : Kb;
        const int i = (blk & 2047) * 256 + tid;   // < SEQ*DIM/8 exactly
        f4 a = ((const f4*)in)[2 * i];
        f4 b = ((const f4*)in)[2 * i + 1];
        s8 w;
        w[0] = f2bf(a[0]); w[1] = f2bf(a[1]); w[2] = f2bf(a[2]); w[3] = f2bf(a[3]);
        w[4] = f2bf(b[0]); w[5] = f2bf(b[1]); w[6] = f2bf(b[2]); w[7] = f2bf(b[3]);
        ((s8*)out)[i] = w;
    } else {
        __shared__ float t[32][33];
        const int b2 = blk - 4096;
        const size_t k0 = (size_t)(b2 & 127) * 32;   // SEQ/32 = 128 k-tiles
        const size_t d0 = (size_t)(b2 >> 7) * 32;    // DIM/32 = 32 d-tiles

        const int r = tid >> 3, c4 = (tid & 7) * 4;
        f4 x = *(const f4*)(Vf + (k0 + r) * DIM + d0 + c4);
        #pragma unroll
        for (int i = 0; i < 4; ++i) t[r][c4 + i] = x[i];
        __syncthreads();

        const int d = tid >> 3, kk = (tid & 7) * 4;
        s4 w;
        #pragma unroll
        for (int i = 0; i < 4; ++i) w[i] = f2bf(t[kk + i][d]);
        *(s4*)(VT + (d0 + d) * SEQ + k0 + kk) = w;
    }
}

// Proven fp32 softmax: applies scale, writes bf16 P in place (lda 8192).
__global__ __launch_bounds__(256) void softmax_rows(float* __restrict__ scores)
{
    const int tid = threadIdx.x;
    float* srow = scores + (size_t)blockIdx.x * SEQ;
    const float SCALE = 0.03125f;

    f4 v[4];
    float mx = -3.4e38f;
    #pragma unroll
    for (int j = 0; j < 4; ++j) {
        v[j] = *(const f4*)(srow + (size_t)(j * 256 + tid) * 4);
        #pragma unroll
        for (int i = 0; i < 4; ++i) {
            v[j][i] *= SCALE;
            mx = fmaxf(mx, v[j][i]);
        }
    }
    #pragma unroll
    for (int o = 32; o > 0; o >>= 1) mx = fmaxf(mx, __shfl_xor(mx, o));
    __shared__ float red[4];
    if ((tid & 63) == 0) red[tid >> 6] = mx;
    __syncthreads();
    mx = fmaxf(fmaxf(red[0], red[1]), fmaxf(red[2], red[3]));

    float sum = 0.f;
    #pragma unroll
    for (int j = 0; j < 4; ++j)
        #pragma unroll
        for (int i = 0; i < 4; ++i) {
            const float e = __expf(v[j][i] - mx);
            v[j][i] = e;
            sum += e;
        }
    #pragma unroll
    for (int o = 32; o > 0; o >>= 1) sum += __shfl_xor(sum, o);
    __syncthreads();
    if ((tid & 63) == 0) red[tid >> 6] = sum;
    __syncthreads();
    const float inv = 1.f / (red[0] + red[1] + red[2] + red[3]);

    short* prow = (short*)srow;
    #pragma unroll
    for (int j = 0; j < 4; ++j) {
        s4 w;
        #pragma unroll
        for (int i = 0; i < 4; ++i) w[i] = f2bf(v[j][i] * inv);
        *(s4*)(prow + (size_t)(j * 256 + tid) * 4) = w;
    }
}

extern "C" void kernel_launch(void* const* d_in, const int* in_sizes, int n_in,
                              void* d_out, int out_size, void* d_ws, size_t ws_size,
                              hipStream_t stream) {
    const float* Q    = (const float*)d_in[0];
    const float* Km   = (const float*)d_in[1];
    const float* V    = (const float*)d_in[2];
    const float* W    = (const float*)d_in[3];
    const float* bias = (const float*)d_in[4];
    float* out = (float*)d_out;

    // ws: ctx bf16 64MB | Qb 8MB | Kb 8MB | VT 8MB | Wb 2MB
    short* ctx = (short*)d_ws;
    short* Qb  = ctx + (size_t)NB * SEQ * DIM;
    short* Kb  = Qb + (size_t)SEQ * DIM;
    short* VT  = Kb + (size_t)SEQ * DIM;
    short* Wb  = VT + (size_t)SEQ * DIM;
    float* scores = out;   // d_out doubles as per-batch fp32 score scratch

    const dim3 blk256(256), blk512(512);
    conv_bf16<<<DIM * DIM / 2048, blk256, 0, stream>>>(W, Wb, DIM * DIM / 8);

    for (int b = 0; b < NB; ++b) {
        const float* Qf = Q  + (size_t)b * SEQ * DIM;
        const float* Kf = Km + (size_t)b * SEQ * DIM;
        const float* Vf = V  + (size_t)b * SEQ * DIM;
        short* ctxb = ctx + (size_t)b * SEQ * DIM;

        // fused Q-conv + K-conv + V-transpose (1 launch instead of 3)
        prep_batch<<<dim3(8192), blk256, 0, stream>>>(Qf, Kf, Vf, Qb, Kb, VT);

        // scores = Qb * Kb^T (fp32 out; scale applied in softmax)
        gemm256<0><<<dim3(256, 1), blk512, 0, stream>>>(
            Qb, DIM, Kb, DIM, scores, SEQ, nullptr, DIM / 32, 16);

        softmax_rows<<<dim3(SEQ), blk256, 0, stream>>>(scores);

        // PV: P bf16 packed at lda 8192
        gemm_bt<true, false><<<dim3(32 * 8), blk256, 0, stream>>>(
            (const short*)scores, 8192, VT, SEQ, ctxb, DIM, nullptr, SEQ / 32, 8);
    }

    // proj: out = ctx * W^T + bias
    gemm256<0><<<dim3(512, 1), blk512, 0, stream>>>(
        ctx, DIM, Wb, DIM, out, DIM, bias, DIM / 32, 4);
}

// Round 10
// 1235.778 us; speedup vs baseline: 1.2329x; 1.0053x over previous
//
#include <hip/hip_runtime.h>
#include <hip/hip_bf16.h>

typedef __attribute__((ext_vector_type(4))) float f4;
typedef __attribute__((ext_vector_type(4))) short s4;
typedef __attribute__((ext_vector_type(8))) short s8;

#define SEQ 4096
#define DIM 1024
#define NB 8

__device__ inline short f2bf(float f) {
    return __builtin_bit_cast(short, __float2bfloat16(f));
}

__device__ inline void gload_lds16(const void* g, void* l) {
    __builtin_amdgcn_global_load_lds(
        (const __attribute__((address_space(1))) void*)g,
        (__attribute__((address_space(3))) void*)l, 16, 0, 0);
}

// ===========================================================================
// gemm256: C[M,N] = A[M,K] * B[N,K]^T. bf16 in, fp32 accum.
// 256x256 tile, BK=32, 8 waves (2Mx4N). 4-deep LDS ring (128 KB), raw
// s_barrier + counted vmcnt. NEW this round: fragment reads software-
// pipelined one K-tile ahead (double register set afA/afB), so ds_read
// issue overlaps MFMA issue within each wave. End-of-iter wait is
// vmcnt(4): tiles <= t+1 are cross-wave landed at iter-t start, making
// the one-ahead LDFRAG(t+1) race-free. nt must be EVEN (always 32 here).
// Swizzle: LDS slot s at row r holds global chunk s ^ ((r>>1)&3).
// OUT: 0 = fp32 (+bias if non-null).
// ===========================================================================
template<int OUT>
__global__ __launch_bounds__(512, 2) void gemm256(
    const short* __restrict__ A, size_t lda,
    const short* __restrict__ B, size_t ldb,
    void* __restrict__ C, size_t ldc,
    const float* __restrict__ bias, int nt, int gridN)
{
    __shared__ short lds[4 * 16384];   // 4 bufs x {A 8192, B 8192} shorts
    const int tid  = threadIdx.x;
    const int lane = tid & 63;
    const int wave = tid >> 6;

    const int nwg = gridDim.x;
    int wg = blockIdx.x;
    wg = (wg & 7) * (nwg >> 3) + (wg >> 3);   // bijective (nwg % 8 == 0)
    const size_t tm = (size_t)(wg / gridN) * 256;
    const size_t tn = (size_t)(wg % gridN) * 256;

    const int srow   = wave * 16 + (lane >> 2);
    const int schunk = lane & 3;
    const int sc     = schunk ^ ((srow >> 1) & 3);
    const short* pA = A + (tm + srow) * lda + sc * 8;
    const short* pB = B + (tn + srow) * ldb + sc * 8;
    const size_t a128 = (size_t)128 * lda;
    const size_t b128 = (size_t)128 * ldb;
    const int ldst = wave * 512 + lane * 8;

    const int fr = lane & 15, kg = lane >> 4;
    const int ck = kg ^ ((fr >> 1) & 3);
    const int wr = wave >> 2, wc = wave & 3;

    auto STAGE = [&](int t) {
        short* base = lds + (t & 3) * 16384;
        const size_t k0 = (size_t)t * 32;
        gload_lds16(pA + k0,        base + ldst);
        gload_lds16(pA + a128 + k0, base + 4096 + ldst);
        gload_lds16(pB + k0,        base + 8192 + ldst);
        gload_lds16(pB + b128 + k0, base + 12288 + ldst);
    };

    f4 acc[8][4];
    #pragma unroll
    for (int m = 0; m < 8; ++m)
        #pragma unroll
        for (int n = 0; n < 4; ++n)
            acc[m][n] = (f4){0.f, 0.f, 0.f, 0.f};

    auto LDFRAG = [&](int t, s8 (&af)[8], s8 (&bf)[4]) {
        const short* lA = lds + (t & 3) * 16384;
        const short* lB = lA + 8192;
        #pragma unroll
        for (int m = 0; m < 8; ++m) {
            const int row = wr * 128 + m * 16 + fr;
            af[m] = *(const s8*)(lA + row * 32 + ck * 8);
        }
        #pragma unroll
        for (int n = 0; n < 4; ++n) {
            const int row = wc * 64 + n * 16 + fr;
            bf[n] = *(const s8*)(lB + row * 32 + ck * 8);
        }
    };

    auto MM = [&](const s8 (&af)[8], const s8 (&bf)[4]) {
        __builtin_amdgcn_s_setprio(1);
        #pragma unroll
        for (int m = 0; m < 8; ++m)
            #pragma unroll
            for (int n = 0; n < 4; ++n)
                acc[m][n] = __builtin_amdgcn_mfma_f32_16x16x32_bf16(af[m], bf[n], acc[m][n], 0, 0, 0);
        __builtin_amdgcn_s_setprio(0);
    };

    s8 afA[8], bfA[4], afB[8], bfB[4];

    // Prologue: stage 3 tiles; vmcnt(4) -> tiles 0 AND 1 landed (this wave);
    // barrier makes that cross-wave. Then preload tile-0 fragments.
    STAGE(0); STAGE(1); STAGE(2);
    asm volatile("s_waitcnt vmcnt(4)" ::: "memory");
    __builtin_amdgcn_s_barrier();
    __builtin_amdgcn_sched_barrier(0);
    LDFRAG(0, afA, bfA);

    for (int t = 0; t < nt; t += 2) {
        // ---- sub-iter t (compute A-set, prefetch frags of t+1 into B-set)
        if (t + 3 < nt) STAGE(t + 3);       // writes buf[(t-1)&3], released
        LDFRAG(t + 1, afB, bfB);            // t+1 landed & barrier'd
        MM(afA, bfA);                       // no dep on LDFRAG above
        if (t + 3 < nt) {
            asm volatile("s_waitcnt vmcnt(4)" ::: "memory");  // t+2 landed
        } else if (t + 2 < nt) {
            asm volatile("s_waitcnt vmcnt(0)" ::: "memory");
        }
        __builtin_amdgcn_s_barrier();       // t+1 < nt always (nt even)
        __builtin_amdgcn_sched_barrier(0);

        // ---- sub-iter t+1 (compute B-set, prefetch frags of t+2 into A-set)
        if (t + 4 < nt) STAGE(t + 4);
        if (t + 2 < nt) LDFRAG(t + 2, afA, bfA);
        MM(afB, bfB);
        if (t + 4 < nt) {
            asm volatile("s_waitcnt vmcnt(4)" ::: "memory");  // t+3 landed
        } else if (t + 3 < nt) {
            asm volatile("s_waitcnt vmcnt(0)" ::: "memory");
        }
        if (t + 2 < nt) {
            __builtin_amdgcn_s_barrier();
            __builtin_amdgcn_sched_barrier(0);
        }
    }

    const int cg = lane >> 4, cl = lane & 15;
    #pragma unroll
    for (int m = 0; m < 8; ++m) {
        #pragma unroll
        for (int n = 0; n < 4; ++n) {
            const size_t grow = tm + wr * 128 + m * 16 + cg * 4;
            const size_t gcol = tn + wc * 64 + n * 16 + cl;
            float bv = 0.f;
            if constexpr (OUT == 0) { if (bias) bv = bias[gcol]; }
            #pragma unroll
            for (int i = 0; i < 4; ++i) {
                const float val = acc[m][n][i] + bv;
                ((float*)C)[(grow + i) * ldc + gcol] = val;
            }
        }
    }
}

// ===========================================================================
// Round-2 proven 128x128 GEMM (PV) — unchanged.
// ===========================================================================
template<bool OBF16, bool BIAS>
__global__ __launch_bounds__(256, 2) void gemm_bt(
    const short* __restrict__ A, size_t lda,
    const short* __restrict__ B, size_t ldb,
    void* __restrict__ C, size_t ldc,
    const float* __restrict__ bias, int kIters, int gridN)
{
    __shared__ short lsA[128 * 32];
    __shared__ short lsB[128 * 32];
    const int tid  = threadIdx.x;
    const int lane = tid & 63;
    const int wave = tid >> 6;

    const int nwg = gridDim.x;
    int wg = blockIdx.x;
    wg = (wg & 7) * (nwg >> 3) + (wg >> 3);
    const size_t tm = (size_t)(wg / gridN) * 128;
    const size_t tn = (size_t)(wg % gridN) * 128;

    const int wr = wave >> 1, wc = wave & 1;
    const int fr = lane & 15, kg = lane >> 4;
    const int fxor = (fr >> 1) & 3;
    const int sl_row0 = wave * 32 + (lane >> 2);
    const int sl_c    = (lane & 3) ^ ((lane >> 3) & 3);

    f4 acc[4][4];
    #pragma unroll
    for (int m = 0; m < 4; ++m)
        #pragma unroll
        for (int n = 0; n < 4; ++n)
            acc[m][n] = (f4){0.f, 0.f, 0.f, 0.f};

    for (int kt = 0; kt < kIters; ++kt) {
        const size_t k0 = (size_t)kt * 32;
        #pragma unroll
        for (int j = 0; j < 2; ++j) {
            const int row = sl_row0 + j * 16;
            gload_lds16(A + (tm + row) * lda + k0 + sl_c * 8, lsA + (wave * 2 + j) * 512 + lane * 8);
            gload_lds16(B + (tn + row) * ldb + k0 + sl_c * 8, lsB + (wave * 2 + j) * 512 + lane * 8);
        }
        __syncthreads();

        s8 af[4], bf[4];
        #pragma unroll
        for (int m = 0; m < 4; ++m)
            af[m] = *(const s8*)(lsA + (wr * 64 + m * 16 + fr) * 32 + (kg ^ fxor) * 8);
        #pragma unroll
        for (int n = 0; n < 4; ++n)
            bf[n] = *(const s8*)(lsB + (wc * 64 + n * 16 + fr) * 32 + (kg ^ fxor) * 8);

        #pragma unroll
        for (int m = 0; m < 4; ++m)
            #pragma unroll
            for (int n = 0; n < 4; ++n)
                acc[m][n] = __builtin_amdgcn_mfma_f32_16x16x32_bf16(af[m], bf[n], acc[m][n], 0, 0, 0);
        __syncthreads();
    }

    const int cg = lane >> 4, cl = lane & 15;
    #pragma unroll
    for (int m = 0; m < 4; ++m) {
        #pragma unroll
        for (int n = 0; n < 4; ++n) {
            const size_t grow = tm + wr * 64 + m * 16 + cg * 4;
            const size_t gcol = tn + wc * 64 + n * 16 + cl;
            float bv = 0.f;
            if constexpr (BIAS) bv = bias[gcol];
            #pragma unroll
            for (int i = 0; i < 4; ++i) {
                const float val = acc[m][n][i] + bv;
                if constexpr (OBF16)
                    ((short*)C)[(grow + i) * ldc + gcol] = f2bf(val);
                else
                    ((float*)C)[(grow + i) * ldc + gcol] = val;
            }
        }
    }
}

// fp32 -> bf16, 8 elements/thread (W only).
__global__ __launch_bounds__(256) void conv_bf16(const float* __restrict__ in,
                                                 short* __restrict__ out, int n8)
{
    const int i = blockIdx.x * 256 + threadIdx.x;
    if (i >= n8) return;
    f4 a = ((const f4*)in)[2 * i];
    f4 b = ((const f4*)in)[2 * i + 1];
    s8 w;
    w[0] = f2bf(a[0]); w[1] = f2bf(a[1]); w[2] = f2bf(a[2]); w[3] = f2bf(a[3]);
    w[4] = f2bf(b[0]); w[5] = f2bf(b[1]); w[6] = f2bf(b[2]); w[7] = f2bf(b[3]);
    ((s8*)out)[i] = w;
}

// ===========================================================================
// prep_batch: one launch per batch doing Q-conv, K-conv, V-transpose.
// ===========================================================================
__global__ __launch_bounds__(256) void prep_batch(
    const float* __restrict__ Qf, const float* __restrict__ Kf,
    const float* __restrict__ Vf,
    short* __restrict__ Qb, short* __restrict__ Kb, short* __restrict__ VT)
{
    const int tid = threadIdx.x;
    const int blk = blockIdx.x;

    if (blk < 4096) {
        const float* in = (blk < 2048) ? Qf : Kf;
        short* out      = (blk < 2048) ? Qb : Kb;
        const int i = (blk & 2047) * 256 + tid;
        f4 a = ((const f4*)in)[2 * i];
        f4 b = ((const f4*)in)[2 * i + 1];
        s8 w;
        w[0] = f2bf(a[0]); w[1] = f2bf(a[1]); w[2] = f2bf(a[2]); w[3] = f2bf(a[3]);
        w[4] = f2bf(b[0]); w[5] = f2bf(b[1]); w[6] = f2bf(b[2]); w[7] = f2bf(b[3]);
        ((s8*)out)[i] = w;
    } else {
        __shared__ float t[32][33];
        const int b2 = blk - 4096;
        const size_t k0 = (size_t)(b2 & 127) * 32;
        const size_t d0 = (size_t)(b2 >> 7) * 32;

        const int r = tid >> 3, c4 = (tid & 7) * 4;
        f4 x = *(const f4*)(Vf + (k0 + r) * DIM + d0 + c4);
        #pragma unroll
        for (int i = 0; i < 4; ++i) t[r][c4 + i] = x[i];
        __syncthreads();

        const int d = tid >> 3, kk = (tid & 7) * 4;
        s4 w;
        #pragma unroll
        for (int i = 0; i < 4; ++i) w[i] = f2bf(t[kk + i][d]);
        *(s4*)(VT + (d0 + d) * SEQ + k0 + kk) = w;
    }
}

// Proven fp32 softmax: applies scale, writes bf16 P in place (lda 8192).
__global__ __launch_bounds__(256) void softmax_rows(float* __restrict__ scores)
{
    const int tid = threadIdx.x;
    float* srow = scores + (size_t)blockIdx.x * SEQ;
    const float SCALE = 0.03125f;

    f4 v[4];
    float mx = -3.4e38f;
    #pragma unroll
    for (int j = 0; j < 4; ++j) {
        v[j] = *(const f4*)(srow + (size_t)(j * 256 + tid) * 4);
        #pragma unroll
        for (int i = 0; i < 4; ++i) {
            v[j][i] *= SCALE;
            mx = fmaxf(mx, v[j][i]);
        }
    }
    #pragma unroll
    for (int o = 32; o > 0; o >>= 1) mx = fmaxf(mx, __shfl_xor(mx, o));
    __shared__ float red[4];
    if ((tid & 63) == 0) red[tid >> 6] = mx;
    __syncthreads();
    mx = fmaxf(fmaxf(red[0], red[1]), fmaxf(red[2], red[3]));

    float sum = 0.f;
    #pragma unroll
    for (int j = 0; j < 4; ++j)
        #pragma unroll
        for (int i = 0; i < 4; ++i) {
            const float e = __expf(v[j][i] - mx);
            v[j][i] = e;
            sum += e;
        }
    #pragma unroll
    for (int o = 32; o > 0; o >>= 1) sum += __shfl_xor(sum, o);
    __syncthreads();
    if ((tid & 63) == 0) red[tid >> 6] = sum;
    __syncthreads();
    const float inv = 1.f / (red[0] + red[1] + red[2] + red[3]);

    short* prow = (short*)srow;
    #pragma unroll
    for (int j = 0; j < 4; ++j) {
        s4 w;
        #pragma unroll
        for (int i = 0; i < 4; ++i) w[i] = f2bf(v[j][i] * inv);
        *(s4*)(prow + (size_t)(j * 256 + tid) * 4) = w;
    }
}

extern "C" void kernel_launch(void* const* d_in, const int* in_sizes, int n_in,
                              void* d_out, int out_size, void* d_ws, size_t ws_size,
                              hipStream_t stream) {
    const float* Q    = (const float*)d_in[0];
    const float* Km   = (const float*)d_in[1];
    const float* V    = (const float*)d_in[2];
    const float* W    = (const float*)d_in[3];
    const float* bias = (const float*)d_in[4];
    float* out = (float*)d_out;

    // ws: ctx bf16 64MB | Qb 8MB | Kb 8MB | VT 8MB | Wb 2MB
    short* ctx = (short*)d_ws;
    short* Qb  = ctx + (size_t)NB * SEQ * DIM;
    short* Kb  = Qb + (size_t)SEQ * DIM;
    short* VT  = Kb + (size_t)SEQ * DIM;
    short* Wb  = VT + (size_t)SEQ * DIM;
    float* scores = out;   // d_out doubles as per-batch fp32 score scratch

    const dim3 blk256(256), blk512(512);
    conv_bf16<<<DIM * DIM / 2048, blk256, 0, stream>>>(W, Wb, DIM * DIM / 8);

    for (int b = 0; b < NB; ++b) {
        const float* Qf = Q  + (size_t)b * SEQ * DIM;
        const float* Kf = Km + (size_t)b * SEQ * DIM;
        const float* Vf = V  + (size_t)b * SEQ * DIM;
        short* ctxb = ctx + (size_t)b * SEQ * DIM;

        prep_batch<<<dim3(8192), blk256, 0, stream>>>(Qf, Kf, Vf, Qb, Kb, VT);

        // scores = Qb * Kb^T (fp32 out; scale applied in softmax)
        gemm256<0><<<dim3(256, 1), blk512, 0, stream>>>(
            Qb, DIM, Kb, DIM, scores, SEQ, nullptr, DIM / 32, 16);

        softmax_rows<<<dim3(SEQ), blk256, 0, stream>>>(scores);

        // PV: P bf16 packed at lda 8192
        gemm_bt<true, false><<<dim3(32 * 8), blk256, 0, stream>>>(
            (const short*)scores, 8192, VT, SEQ, ctxb, DIM, nullptr, SEQ / 32, 8);
    }

    // proj: out = ctx * W^T + bias
    gemm256<0><<<dim3(512, 1), blk512, 0, stream>>>(
        ctx, DIM, Wb, DIM, out, DIM, bias, DIM / 32, 4);
}

// Round 11
// 1219.508 us; speedup vs baseline: 1.2494x; 1.0133x over previous
//
#include <hip/hip_runtime.h>
#include <hip/hip_bf16.h>

typedef __attribute__((ext_vector_type(4))) float f4;
typedef __attribute__((ext_vector_type(4))) short s4;
typedef __attribute__((ext_vector_type(8))) short s8;

#define SEQ 4096
#define DIM 1024
#define NB 8

__device__ inline short f2bf(float f) {
    return __builtin_bit_cast(short, __float2bfloat16(f));
}

__device__ inline void gload_lds16(const void* g, void* l) {
    __builtin_amdgcn_global_load_lds(
        (const __attribute__((address_space(1))) void*)g,
        (__attribute__((address_space(3))) void*)l, 16, 0, 0);
}

// ===========================================================================
// gemm256: C[M,N] = A[M,K] * B[N,K]^T. bf16 in, fp32 accum.
// 256x256 tile, BK=64 (NEW), 8 waves (2Mx4N), ring-2 LDS (128 KB) with the
// spill-proof drain schedule (round-6-validated): STAGE(t+1) issued before
// compute of tile t, one __syncthreads per K-step. With BK=64 the per-iter
// compute (~1900 cy) exceeds HBM latency, so the drain is ~free and barrier
// count halves vs BK=32.
// LDS row = 64 bf16 = 8 chunks of 16B; slot s at row r holds global chunk
// s ^ (r&7) (involution; frag reads <=2-way conflict).
// Accumulation order identical to BK=32 version (same K-chunk sequence).
// OUT: 0 = fp32 (+bias if non-null).
// ===========================================================================
template<int OUT>
__global__ __launch_bounds__(512, 2) void gemm256(
    const short* __restrict__ A, size_t lda,
    const short* __restrict__ B, size_t ldb,
    void* __restrict__ C, size_t ldc,
    const float* __restrict__ bias, int nt, int gridN)
{
    __shared__ short lds[2 * 32768];   // 2 bufs x {A 16384, B 16384} shorts
    const int tid  = threadIdx.x;
    const int lane = tid & 63;
    const int wave = tid >> 6;

    const int nwg = gridDim.x;
    int wg = blockIdx.x;
    wg = (wg & 7) * (nwg >> 3) + (wg >> 3);   // bijective (nwg % 8 == 0)
    const size_t tm = (size_t)(wg / gridN) * 256;
    const size_t tn = (size_t)(wg % gridN) * 256;

    // staging: thread covers rows j*64 + (tid>>3), j=0..3; 16B slot tid&7.
    // LDS dest is linear per lane: ldst = wave*512 + lane*8 shorts.
    const int srow = tid >> 3;                 // 0..63
    const int slot = tid & 7;
    const int sc   = slot ^ (srow & 7);        // source chunk (j-invariant)
    const short* pA = A + (tm + srow) * lda + sc * 8;
    const short* pB = B + (tn + srow) * ldb + sc * 8;
    const int ldst = srow * 64 + slot * 8;

    const int fr = lane & 15, kg = lane >> 4;
    const int wr = wave >> 2, wc = wave & 3;

    auto STAGE = [&](int t) {
        short* bufA = lds + (t & 1) * 32768;
        short* bufB = bufA + 16384;
        const size_t k0 = (size_t)t * 64;
        #pragma unroll
        for (int j = 0; j < 4; ++j) {
            gload_lds16(pA + (size_t)(j * 64) * lda + k0, bufA + j * 4096 + ldst);
            gload_lds16(pB + (size_t)(j * 64) * ldb + k0, bufB + j * 4096 + ldst);
        }
    };

    f4 acc[8][4];
    #pragma unroll
    for (int m = 0; m < 8; ++m)
        #pragma unroll
        for (int n = 0; n < 4; ++n)
            acc[m][n] = (f4){0.f, 0.f, 0.f, 0.f};

    STAGE(0);
    __syncthreads();                       // drains vmcnt(0): buf0 ready

    for (int t = 0; t < nt; ++t) {
        if (t + 1 < nt) STAGE(t + 1);      // other buf; its readers finished
                                           // at the barrier ending iter t-1

        const short* bufA = lds + (t & 1) * 32768;
        const short* bufB = bufA + 16384;
        s8 af[2][8], bf[2][4];
        #pragma unroll
        for (int kh = 0; kh < 2; ++kh) {
            #pragma unroll
            for (int m = 0; m < 8; ++m) {
                const int row = wr * 128 + m * 16 + fr;
                const int c   = kh * 4 + kg;
                af[kh][m] = *(const s8*)(bufA + row * 64 + (c ^ (row & 7)) * 8);
            }
            #pragma unroll
            for (int n = 0; n < 4; ++n) {
                const int row = wc * 64 + n * 16 + fr;
                const int c   = kh * 4 + kg;
                bf[kh][n] = *(const s8*)(bufB + row * 64 + (c ^ (row & 7)) * 8);
            }
        }
        __builtin_amdgcn_s_setprio(1);
        #pragma unroll
        for (int kh = 0; kh < 2; ++kh)
            #pragma unroll
            for (int m = 0; m < 8; ++m)
                #pragma unroll
                for (int n = 0; n < 4; ++n)
                    acc[m][n] = __builtin_amdgcn_mfma_f32_16x16x32_bf16(
                        af[kh][m], bf[kh][n], acc[m][n], 0, 0, 0);
        __builtin_amdgcn_s_setprio(0);

        __syncthreads();   // all reads of buf[t&1] done + STAGE(t+1) landed
    }

    const int cg = lane >> 4, cl = lane & 15;
    #pragma unroll
    for (int m = 0; m < 8; ++m) {
        #pragma unroll
        for (int n = 0; n < 4; ++n) {
            const size_t grow = tm + wr * 128 + m * 16 + cg * 4;
            const size_t gcol = tn + wc * 64 + n * 16 + cl;
            float bv = 0.f;
            if constexpr (OUT == 0) { if (bias) bv = bias[gcol]; }
            #pragma unroll
            for (int i = 0; i < 4; ++i) {
                const float val = acc[m][n][i] + bv;
                ((float*)C)[(grow + i) * ldc + gcol] = val;
            }
        }
    }
}

// ===========================================================================
// Round-2 proven 128x128 GEMM (PV) — unchanged.
// ===========================================================================
template<bool OBF16, bool BIAS>
__global__ __launch_bounds__(256, 2) void gemm_bt(
    const short* __restrict__ A, size_t lda,
    const short* __restrict__ B, size_t ldb,
    void* __restrict__ C, size_t ldc,
    const float* __restrict__ bias, int kIters, int gridN)
{
    __shared__ short lsA[128 * 32];
    __shared__ short lsB[128 * 32];
    const int tid  = threadIdx.x;
    const int lane = tid & 63;
    const int wave = tid >> 6;

    const int nwg = gridDim.x;
    int wg = blockIdx.x;
    wg = (wg & 7) * (nwg >> 3) + (wg >> 3);
    const size_t tm = (size_t)(wg / gridN) * 128;
    const size_t tn = (size_t)(wg % gridN) * 128;

    const int wr = wave >> 1, wc = wave & 1;
    const int fr = lane & 15, kg = lane >> 4;
    const int fxor = (fr >> 1) & 3;
    const int sl_row0 = wave * 32 + (lane >> 2);
    const int sl_c    = (lane & 3) ^ ((lane >> 3) & 3);

    f4 acc[4][4];
    #pragma unroll
    for (int m = 0; m < 4; ++m)
        #pragma unroll
        for (int n = 0; n < 4; ++n)
            acc[m][n] = (f4){0.f, 0.f, 0.f, 0.f};

    for (int kt = 0; kt < kIters; ++kt) {
        const size_t k0 = (size_t)kt * 32;
        #pragma unroll
        for (int j = 0; j < 2; ++j) {
            const int row = sl_row0 + j * 16;
            gload_lds16(A + (tm + row) * lda + k0 + sl_c * 8, lsA + (wave * 2 + j) * 512 + lane * 8);
            gload_lds16(B + (tn + row) * ldb + k0 + sl_c * 8, lsB + (wave * 2 + j) * 512 + lane * 8);
        }
        __syncthreads();

        s8 af[4], bf[4];
        #pragma unroll
        for (int m = 0; m < 4; ++m)
            af[m] = *(const s8*)(lsA + (wr * 64 + m * 16 + fr) * 32 + (kg ^ fxor) * 8);
        #pragma unroll
        for (int n = 0; n < 4; ++n)
            bf[n] = *(const s8*)(lsB + (wc * 64 + n * 16 + fr) * 32 + (kg ^ fxor) * 8);

        #pragma unroll
        for (int m = 0; m < 4; ++m)
            #pragma unroll
            for (int n = 0; n < 4; ++n)
                acc[m][n] = __builtin_amdgcn_mfma_f32_16x16x32_bf16(af[m], bf[n], acc[m][n], 0, 0, 0);
        __syncthreads();
    }

    const int cg = lane >> 4, cl = lane & 15;
    #pragma unroll
    for (int m = 0; m < 4; ++m) {
        #pragma unroll
        for (int n = 0; n < 4; ++n) {
            const size_t grow = tm + wr * 64 + m * 16 + cg * 4;
            const size_t gcol = tn + wc * 64 + n * 16 + cl;
            float bv = 0.f;
            if constexpr (BIAS) bv = bias[gcol];
            #pragma unroll
            for (int i = 0; i < 4; ++i) {
                const float val = acc[m][n][i] + bv;
                if constexpr (OBF16)
                    ((short*)C)[(grow + i) * ldc + gcol] = f2bf(val);
                else
                    ((float*)C)[(grow + i) * ldc + gcol] = val;
            }
        }
    }
}

// fp32 -> bf16, 8 elements/thread (W only).
__global__ __launch_bounds__(256) void conv_bf16(const float* __restrict__ in,
                                                 short* __restrict__ out, int n8)
{
    const int i = blockIdx.x * 256 + threadIdx.x;
    if (i >= n8) return;
    f4 a = ((const f4*)in)[2 * i];
    f4 b = ((const f4*)in)[2 * i + 1];
    s8 w;
    w[0] = f2bf(a[0]); w[1] = f2bf(a[1]); w[2] = f2bf(a[2]); w[3] = f2bf(a[3]);
    w[4] = f2bf(b[0]); w[5] = f2bf(b[1]); w[6] = f2bf(b[2]); w[7] = f2bf(b[3]);
    ((s8*)out)[i] = w;
}

// ===========================================================================
// prep_batch: one launch per batch doing Q-conv, K-conv, V-transpose.
// ===========================================================================
__global__ __launch_bounds__(256) void prep_batch(
    const float* __restrict__ Qf, const float* __restrict__ Kf,
    const float* __restrict__ Vf,
    short* __restrict__ Qb, short* __restrict__ Kb, short* __restrict__ VT)
{
    const int tid = threadIdx.x;
    const int blk = blockIdx.x;

    if (blk < 4096) {
        const float* in = (blk < 2048) ? Qf : Kf;
        short* out      = (blk < 2048) ? Qb : Kb;
        const int i = (blk & 2047) * 256 + tid;
        f4 a = ((const f4*)in)[2 * i];
        f4 b = ((const f4*)in)[2 * i + 1];
        s8 w;
        w[0] = f2bf(a[0]); w[1] = f2bf(a[1]); w[2] = f2bf(a[2]); w[3] = f2bf(a[3]);
        w[4] = f2bf(b[0]); w[5] = f2bf(b[1]); w[6] = f2bf(b[2]); w[7] = f2bf(b[3]);
        ((s8*)out)[i] = w;
    } else {
        __shared__ float t[32][33];
        const int b2 = blk - 4096;
        const size_t k0 = (size_t)(b2 & 127) * 32;
        const size_t d0 = (size_t)(b2 >> 7) * 32;

        const int r = tid >> 3, c4 = (tid & 7) * 4;
        f4 x = *(const f4*)(Vf + (k0 + r) * DIM + d0 + c4);
        #pragma unroll
        for (int i = 0; i < 4; ++i) t[r][c4 + i] = x[i];
        __syncthreads();

        const int d = tid >> 3, kk = (tid & 7) * 4;
        s4 w;
        #pragma unroll
        for (int i = 0; i < 4; ++i) w[i] = f2bf(t[kk + i][d]);
        *(s4*)(VT + (d0 + d) * SEQ + k0 + kk) = w;
    }
}

// Proven fp32 softmax: applies scale, writes bf16 P in place (lda 8192).
__global__ __launch_bounds__(256) void softmax_rows(float* __restrict__ scores)
{
    const int tid = threadIdx.x;
    float* srow = scores + (size_t)blockIdx.x * SEQ;
    const float SCALE = 0.03125f;

    f4 v[4];
    float mx = -3.4e38f;
    #pragma unroll
    for (int j = 0; j < 4; ++j) {
        v[j] = *(const f4*)(srow + (size_t)(j * 256 + tid) * 4);
        #pragma unroll
        for (int i = 0; i < 4; ++i) {
            v[j][i] *= SCALE;
            mx = fmaxf(mx, v[j][i]);
        }
    }
    #pragma unroll
    for (int o = 32; o > 0; o >>= 1) mx = fmaxf(mx, __shfl_xor(mx, o));
    __shared__ float red[4];
    if ((tid & 63) == 0) red[tid >> 6] = mx;
    __syncthreads();
    mx = fmaxf(fmaxf(red[0], red[1]), fmaxf(red[2], red[3]));

    float sum = 0.f;
    #pragma unroll
    for (int j = 0; j < 4; ++j)
        #pragma unroll
        for (int i = 0; i < 4; ++i) {
            const float e = __expf(v[j][i] - mx);
            v[j][i] = e;
            sum += e;
        }
    #pragma unroll
    for (int o = 32; o > 0; o >>= 1) sum += __shfl_xor(sum, o);
    __syncthreads();
    if ((tid & 63) == 0) red[tid >> 6] = sum;
    __syncthreads();
    const float inv = 1.f / (red[0] + red[1] + red[2] + red[3]);

    short* prow = (short*)srow;
    #pragma unroll
    for (int j = 0; j < 4; ++j) {
        s4 w;
        #pragma unroll
        for (int i = 0; i < 4; ++i) w[i] = f2bf(v[j][i] * inv);
        *(s4*)(prow + (size_t)(j * 256 + tid) * 4) = w;
    }
}

extern "C" void kernel_launch(void* const* d_in, const int* in_sizes, int n_in,
                              void* d_out, int out_size, void* d_ws, size_t ws_size,
                              hipStream_t stream) {
    const float* Q    = (const float*)d_in[0];
    const float* Km   = (const float*)d_in[1];
    const float* V    = (const float*)d_in[2];
    const float* W    = (const float*)d_in[3];
    const float* bias = (const float*)d_in[4];
    float* out = (float*)d_out;

    // ws: ctx bf16 64MB | Qb 8MB | Kb 8MB | VT 8MB | Wb 2MB
    short* ctx = (short*)d_ws;
    short* Qb  = ctx + (size_t)NB * SEQ * DIM;
    short* Kb  = Qb + (size_t)SEQ * DIM;
    short* VT  = Kb + (size_t)SEQ * DIM;
    short* Wb  = VT + (size_t)SEQ * DIM;
    float* scores = out;   // d_out doubles as per-batch fp32 score scratch

    const dim3 blk256(256), blk512(512);
    conv_bf16<<<DIM * DIM / 2048, blk256, 0, stream>>>(W, Wb, DIM * DIM / 8);

    for (int b = 0; b < NB; ++b) {
        const float* Qf = Q  + (size_t)b * SEQ * DIM;
        const float* Kf = Km + (size_t)b * SEQ * DIM;
        const float* Vf = V  + (size_t)b * SEQ * DIM;
        short* ctxb = ctx + (size_t)b * SEQ * DIM;

        prep_batch<<<dim3(8192), blk256, 0, stream>>>(Qf, Kf, Vf, Qb, Kb, VT);

        // scores = Qb * Kb^T (fp32 out; scale applied in softmax); nt = 1024/64
        gemm256<0><<<dim3(256, 1), blk512, 0, stream>>>(
            Qb, DIM, Kb, DIM, scores, SEQ, nullptr, DIM / 64, 16);

        softmax_rows<<<dim3(SEQ), blk256, 0, stream>>>(scores);

        // PV: P bf16 packed at lda 8192
        gemm_bt<true, false><<<dim3(32 * 8), blk256, 0, stream>>>(
            (const short*)scores, 8192, VT, SEQ, ctxb, DIM, nullptr, SEQ / 32, 8);
    }

    // proj: out = ctx * W^T + bias; nt = 1024/64
    gemm256<0><<<dim3(512, 1), blk512, 0, stream>>>(
        ctx, DIM, Wb, DIM, out, DIM, bias, DIM / 64, 4);
}

// Round 12
// 1168.907 us; speedup vs baseline: 1.3035x; 1.0433x over previous
//
#include <hip/hip_runtime.h>
#include <hip/hip_bf16.h>

typedef __attribute__((ext_vector_type(4))) float f4;
typedef __attribute__((ext_vector_type(4))) short s4;
typedef __attribute__((ext_vector_type(8))) short s8;

#define SEQ 4096
#define DIM 1024
#define NB 8

__device__ inline short f2bf(float f) {
    return __builtin_bit_cast(short, __float2bfloat16(f));
}

__device__ inline float bf2f(short s) {
    return __builtin_bit_cast(float, (unsigned)((unsigned short)s) << 16);
}

__device__ inline void gload_lds16(const void* g, void* l) {
    __builtin_amdgcn_global_load_lds(
        (const __attribute__((address_space(1))) void*)g,
        (__attribute__((address_space(3))) void*)l, 16, 0, 0);
}

// ===========================================================================
// gemm256: C[M,N] = A[M,K] * B[N,K]^T. bf16 in, fp32 accum.
// 256x256 tile, BK=64, 8 waves (2Mx4N), ring-2 LDS (128 KB), spill-proof
// drain schedule (validated rounds 6/11). LDS row = 64 bf16 = 8 chunks of
// 16B; slot s at row r holds global chunk s ^ (r&7).
// OUT: 0 = fp32 (+bias if non-null), 2 = bf16 (same f2bf short-store
// pattern as the validated gemm_bt OBF16 epilogue).
// ===========================================================================
template<int OUT>
__global__ __launch_bounds__(512, 2) void gemm256(
    const short* __restrict__ A, size_t lda,
    const short* __restrict__ B, size_t ldb,
    void* __restrict__ C, size_t ldc,
    const float* __restrict__ bias, int nt, int gridN)
{
    __shared__ short lds[2 * 32768];   // 2 bufs x {A 16384, B 16384} shorts
    const int tid  = threadIdx.x;
    const int lane = tid & 63;
    const int wave = tid >> 6;

    const int nwg = gridDim.x;
    int wg = blockIdx.x;
    wg = (wg & 7) * (nwg >> 3) + (wg >> 3);   // bijective (nwg % 8 == 0)
    const size_t tm = (size_t)(wg / gridN) * 256;
    const size_t tn = (size_t)(wg % gridN) * 256;

    const int srow = tid >> 3;                 // 0..63
    const int slot = tid & 7;
    const int sc   = slot ^ (srow & 7);
    const short* pA = A + (tm + srow) * lda + sc * 8;
    const short* pB = B + (tn + srow) * ldb + sc * 8;
    const int ldst = srow * 64 + slot * 8;

    const int fr = lane & 15, kg = lane >> 4;
    const int wr = wave >> 2, wc = wave & 3;

    auto STAGE = [&](int t) {
        short* bufA = lds + (t & 1) * 32768;
        short* bufB = bufA + 16384;
        const size_t k0 = (size_t)t * 64;
        #pragma unroll
        for (int j = 0; j < 4; ++j) {
            gload_lds16(pA + (size_t)(j * 64) * lda + k0, bufA + j * 4096 + ldst);
            gload_lds16(pB + (size_t)(j * 64) * ldb + k0, bufB + j * 4096 + ldst);
        }
    };

    f4 acc[8][4];
    #pragma unroll
    for (int m = 0; m < 8; ++m)
        #pragma unroll
        for (int n = 0; n < 4; ++n)
            acc[m][n] = (f4){0.f, 0.f, 0.f, 0.f};

    STAGE(0);
    __syncthreads();

    for (int t = 0; t < nt; ++t) {
        if (t + 1 < nt) STAGE(t + 1);

        const short* bufA = lds + (t & 1) * 32768;
        const short* bufB = bufA + 16384;
        s8 af[2][8], bf[2][4];
        #pragma unroll
        for (int kh = 0; kh < 2; ++kh) {
            #pragma unroll
            for (int m = 0; m < 8; ++m) {
                const int row = wr * 128 + m * 16 + fr;
                const int c   = kh * 4 + kg;
                af[kh][m] = *(const s8*)(bufA + row * 64 + (c ^ (row & 7)) * 8);
            }
            #pragma unroll
            for (int n = 0; n < 4; ++n) {
                const int row = wc * 64 + n * 16 + fr;
                const int c   = kh * 4 + kg;
                bf[kh][n] = *(const s8*)(bufB + row * 64 + (c ^ (row & 7)) * 8);
            }
        }
        __builtin_amdgcn_s_setprio(1);
        #pragma unroll
        for (int kh = 0; kh < 2; ++kh)
            #pragma unroll
            for (int m = 0; m < 8; ++m)
                #pragma unroll
                for (int n = 0; n < 4; ++n)
                    acc[m][n] = __builtin_amdgcn_mfma_f32_16x16x32_bf16(
                        af[kh][m], bf[kh][n], acc[m][n], 0, 0, 0);
        __builtin_amdgcn_s_setprio(0);

        __syncthreads();
    }

    const int cg = lane >> 4, cl = lane & 15;
    #pragma unroll
    for (int m = 0; m < 8; ++m) {
        #pragma unroll
        for (int n = 0; n < 4; ++n) {
            const size_t grow = tm + wr * 128 + m * 16 + cg * 4;
            const size_t gcol = tn + wc * 64 + n * 16 + cl;
            float bv = 0.f;
            if constexpr (OUT == 0) { if (bias) bv = bias[gcol]; }
            #pragma unroll
            for (int i = 0; i < 4; ++i) {
                const float val = acc[m][n][i] + bv;
                if constexpr (OUT == 0)
                    ((float*)C)[(grow + i) * ldc + gcol] = val;
                else
                    ((short*)C)[(grow + i) * ldc + gcol] = f2bf(val);
            }
        }
    }
}

// ===========================================================================
// Round-2 proven 128x128 GEMM (PV) — unchanged.
// ===========================================================================
template<bool OBF16, bool BIAS>
__global__ __launch_bounds__(256, 2) void gemm_bt(
    const short* __restrict__ A, size_t lda,
    const short* __restrict__ B, size_t ldb,
    void* __restrict__ C, size_t ldc,
    const float* __restrict__ bias, int kIters, int gridN)
{
    __shared__ short lsA[128 * 32];
    __shared__ short lsB[128 * 32];
    const int tid  = threadIdx.x;
    const int lane = tid & 63;
    const int wave = tid >> 6;

    const int nwg = gridDim.x;
    int wg = blockIdx.x;
    wg = (wg & 7) * (nwg >> 3) + (wg >> 3);
    const size_t tm = (size_t)(wg / gridN) * 128;
    const size_t tn = (size_t)(wg % gridN) * 128;

    const int wr = wave >> 1, wc = wave & 1;
    const int fr = lane & 15, kg = lane >> 4;
    const int fxor = (fr >> 1) & 3;
    const int sl_row0 = wave * 32 + (lane >> 2);
    const int sl_c    = (lane & 3) ^ ((lane >> 3) & 3);

    f4 acc[4][4];
    #pragma unroll
    for (int m = 0; m < 4; ++m)
        #pragma unroll
        for (int n = 0; n < 4; ++n)
            acc[m][n] = (f4){0.f, 0.f, 0.f, 0.f};

    for (int kt = 0; kt < kIters; ++kt) {
        const size_t k0 = (size_t)kt * 32;
        #pragma unroll
        for (int j = 0; j < 2; ++j) {
            const int row = sl_row0 + j * 16;
            gload_lds16(A + (tm + row) * lda + k0 + sl_c * 8, lsA + (wave * 2 + j) * 512 + lane * 8);
            gload_lds16(B + (tn + row) * ldb + k0 + sl_c * 8, lsB + (wave * 2 + j) * 512 + lane * 8);
        }
        __syncthreads();

        s8 af[4], bf[4];
        #pragma unroll
        for (int m = 0; m < 4; ++m)
            af[m] = *(const s8*)(lsA + (wr * 64 + m * 16 + fr) * 32 + (kg ^ fxor) * 8);
        #pragma unroll
        for (int n = 0; n < 4; ++n)
            bf[n] = *(const s8*)(lsB + (wc * 64 + n * 16 + fr) * 32 + (kg ^ fxor) * 8);

        #pragma unroll
        for (int m = 0; m < 4; ++m)
            #pragma unroll
            for (int n = 0; n < 4; ++n)
                acc[m][n] = __builtin_amdgcn_mfma_f32_16x16x32_bf16(af[m], bf[n], acc[m][n], 0, 0, 0);
        __syncthreads();
    }

    const int cg = lane >> 4, cl = lane & 15;
    #pragma unroll
    for (int m = 0; m < 4; ++m) {
        #pragma unroll
        for (int n = 0; n < 4; ++n) {
            const size_t grow = tm + wr * 64 + m * 16 + cg * 4;
            const size_t gcol = tn + wc * 64 + n * 16 + cl;
            float bv = 0.f;
            if constexpr (BIAS) bv = bias[gcol];
            #pragma unroll
            for (int i = 0; i < 4; ++i) {
                const float val = acc[m][n][i] + bv;
                if constexpr (OBF16)
                    ((short*)C)[(grow + i) * ldc + gcol] = f2bf(val);
                else
                    ((float*)C)[(grow + i) * ldc + gcol] = val;
            }
        }
    }
}

// fp32 -> bf16, 8 elements/thread (W only).
__global__ __launch_bounds__(256) void conv_bf16(const float* __restrict__ in,
                                                 short* __restrict__ out, int n8)
{
    const int i = blockIdx.x * 256 + threadIdx.x;
    if (i >= n8) return;
    f4 a = ((const f4*)in)[2 * i];
    f4 b = ((const f4*)in)[2 * i + 1];
    s8 w;
    w[0] = f2bf(a[0]); w[1] = f2bf(a[1]); w[2] = f2bf(a[2]); w[3] = f2bf(a[3]);
    w[4] = f2bf(b[0]); w[5] = f2bf(b[1]); w[6] = f2bf(b[2]); w[7] = f2bf(b[3]);
    ((s8*)out)[i] = w;
}

// ===========================================================================
// prep_batch: one launch per batch doing Q-conv, K-conv, V-transpose.
// ===========================================================================
__global__ __launch_bounds__(256) void prep_batch(
    const float* __restrict__ Qf, const float* __restrict__ Kf,
    const float* __restrict__ Vf,
    short* __restrict__ Qb, short* __restrict__ Kb, short* __restrict__ VT)
{
    const int tid = threadIdx.x;
    const int blk = blockIdx.x;

    if (blk < 4096) {
        const float* in = (blk < 2048) ? Qf : Kf;
        short* out      = (blk < 2048) ? Qb : Kb;
        const int i = (blk & 2047) * 256 + tid;
        f4 a = ((const f4*)in)[2 * i];
        f4 b = ((const f4*)in)[2 * i + 1];
        s8 w;
        w[0] = f2bf(a[0]); w[1] = f2bf(a[1]); w[2] = f2bf(a[2]); w[3] = f2bf(a[3]);
        w[4] = f2bf(b[0]); w[5] = f2bf(b[1]); w[6] = f2bf(b[2]); w[7] = f2bf(b[3]);
        ((s8*)out)[i] = w;
    } else {
        __shared__ float t[32][33];
        const int b2 = blk - 4096;
        const size_t k0 = (size_t)(b2 & 127) * 32;
        const size_t d0 = (size_t)(b2 >> 7) * 32;

        const int r = tid >> 3, c4 = (tid & 7) * 4;
        f4 x = *(const f4*)(Vf + (k0 + r) * DIM + d0 + c4);
        #pragma unroll
        for (int i = 0; i < 4; ++i) t[r][c4 + i] = x[i];
        __syncthreads();

        const int d = tid >> 3, kk = (tid & 7) * 4;
        s4 w;
        #pragma unroll
        for (int i = 0; i < 4; ++i) w[i] = f2bf(t[kk + i][d]);
        *(s4*)(VT + (d0 + d) * SEQ + k0 + kk) = w;
    }
}

// Row softmax over 4096 bf16 scores (packed, ld 4096). Structure identical
// to the validated fp32 softmax_rows; loads convert bf16->fp32 via bit-shift
// (no __half intrinsics). Applies scale, writes bf16 P in place.
__global__ __launch_bounds__(256) void softmax_rows_bf(short* __restrict__ scores)
{
    const int tid = threadIdx.x;
    short* srow = scores + (size_t)blockIdx.x * SEQ;
    const float SCALE = 0.03125f;

    float v[16];
    float mx = -3.4e38f;
    #pragma unroll
    for (int j = 0; j < 4; ++j) {
        s4 h = *(const s4*)(srow + (size_t)(j * 256 + tid) * 4);
        #pragma unroll
        for (int i = 0; i < 4; ++i) {
            const float f = bf2f(h[i]) * SCALE;
            v[j * 4 + i] = f;
            mx = fmaxf(mx, f);
        }
    }
    #pragma unroll
    for (int o = 32; o > 0; o >>= 1) mx = fmaxf(mx, __shfl_xor(mx, o));
    __shared__ float red[4];
    if ((tid & 63) == 0) red[tid >> 6] = mx;
    __syncthreads();
    mx = fmaxf(fmaxf(red[0], red[1]), fmaxf(red[2], red[3]));

    float sum = 0.f;
    #pragma unroll
    for (int j = 0; j < 16; ++j) {
        const float e = __expf(v[j] - mx);
        v[j] = e;
        sum += e;
    }
    #pragma unroll
    for (int o = 32; o > 0; o >>= 1) sum += __shfl_xor(sum, o);
    __syncthreads();
    if ((tid & 63) == 0) red[tid >> 6] = sum;
    __syncthreads();
    const float inv = 1.f / (red[0] + red[1] + red[2] + red[3]);

    #pragma unroll
    for (int j = 0; j < 4; ++j) {
        s4 w;
        #pragma unroll
        for (int i = 0; i < 4; ++i) w[i] = f2bf(v[j * 4 + i] * inv);
        *(s4*)(srow + (size_t)(j * 256 + tid) * 4) = w;
    }
}

extern "C" void kernel_launch(void* const* d_in, const int* in_sizes, int n_in,
                              void* d_out, int out_size, void* d_ws, size_t ws_size,
                              hipStream_t stream) {
    const float* Q    = (const float*)d_in[0];
    const float* Km   = (const float*)d_in[1];
    const float* V    = (const float*)d_in[2];
    const float* W    = (const float*)d_in[3];
    const float* bias = (const float*)d_in[4];
    float* out = (float*)d_out;

    // ws: ctx bf16 64MB | Qb 8MB | Kb 8MB | VT 8MB | Wb 2MB
    short* ctx = (short*)d_ws;
    short* Qb  = ctx + (size_t)NB * SEQ * DIM;
    short* Kb  = Qb + (size_t)SEQ * DIM;
    short* VT  = Kb + (size_t)SEQ * DIM;
    short* Wb  = VT + (size_t)SEQ * DIM;
    // Scores: bf16 packed [4096][4096] = 32 MB, living in d_out scratch
    // (overwritten by the final fp32 proj write).
    short* scoresB = (short*)d_out;

    const dim3 blk256(256), blk512(512);
    conv_bf16<<<DIM * DIM / 2048, blk256, 0, stream>>>(W, Wb, DIM * DIM / 8);

    for (int b = 0; b < NB; ++b) {
        const float* Qf = Q  + (size_t)b * SEQ * DIM;
        const float* Kf = Km + (size_t)b * SEQ * DIM;
        const float* Vf = V  + (size_t)b * SEQ * DIM;
        short* ctxb = ctx + (size_t)b * SEQ * DIM;

        prep_batch<<<dim3(8192), blk256, 0, stream>>>(Qf, Kf, Vf, Qb, Kb, VT);

        // scores(bf16, raw) = Qb * Kb^T  (scale applied in softmax)
        gemm256<2><<<dim3(256, 1), blk512, 0, stream>>>(
            Qb, DIM, Kb, DIM, scoresB, SEQ, nullptr, DIM / 64, 16);

        softmax_rows_bf<<<dim3(SEQ), blk256, 0, stream>>>(scoresB);

        // PV: P bf16 packed at lda 4096
        gemm_bt<true, false><<<dim3(32 * 8), blk256, 0, stream>>>(
            scoresB, SEQ, VT, SEQ, ctxb, DIM, nullptr, SEQ / 32, 8);
    }

    // proj: out = ctx * W^T + bias
    gemm256<0><<<dim3(512, 1), blk512, 0, stream>>>(
        ctx, DIM, Wb, DIM, out, DIM, bias, DIM / 64, 4);
}

// Round 13
// 811.084 us; speedup vs baseline: 1.8785x; 1.4412x over previous
//
#include <hip/hip_runtime.h>
#include <hip/hip_bf16.h>

typedef __attribute__((ext_vector_type(4))) float f4;
typedef __attribute__((ext_vector_type(4))) short s4;
typedef __attribute__((ext_vector_type(8))) short s8;

#define SEQ 4096
#define DIM 1024
#define NB 8

__device__ inline short f2bf(float f) {
    return __builtin_bit_cast(short, __float2bfloat16(f));
}

__device__ inline float bf2f(short s) {
    return __builtin_bit_cast(float, (unsigned)((unsigned short)s) << 16);
}

__device__ inline void gload_lds16(const void* g, void* l) {
    __builtin_amdgcn_global_load_lds(
        (const __attribute__((address_space(1))) void*)g,
        (__attribute__((address_space(3))) void*)l, 16, 0, 0);
}

// ===========================================================================
// gemm256: C[M,N] = A[M,K] * B[N,K]^T. bf16 in, fp32 accum.
// 256x256 tile, BK=64, 8 waves (2Mx4N), ring-2 LDS (128 KB), spill-proof
// drain schedule (validated rounds 6/11/12). LDS row = 64 bf16 = 8 chunks
// of 16B; slot s at row r holds global chunk s ^ (r&7).
// Batched via blockIdx.y: bsA/bsB/bsC are ELEMENT strides applied to typed
// pointers (no byte arithmetic — round-4 lesson).
// OUT: 0 = fp32 (+bias if non-null), 2 = bf16.
// ===========================================================================
template<int OUT>
__global__ __launch_bounds__(512, 2) void gemm256(
    const short* __restrict__ A, size_t lda, size_t bsA,
    const short* __restrict__ B, size_t ldb, size_t bsB,
    void* __restrict__ C, size_t ldc, size_t bsC,
    const float* __restrict__ bias, int nt, int gridN)
{
    __shared__ short lds[2 * 32768];   // 2 bufs x {A 16384, B 16384} shorts
    const int tid  = threadIdx.x;
    const int lane = tid & 63;
    const int wave = tid >> 6;

    A += (size_t)blockIdx.y * bsA;
    B += (size_t)blockIdx.y * bsB;
    float* Cf = (float*)C + (size_t)blockIdx.y * bsC;
    short* Cs = (short*)C + (size_t)blockIdx.y * bsC;

    const int nwg = gridDim.x;
    int wg = blockIdx.x;
    wg = (wg & 7) * (nwg >> 3) + (wg >> 3);   // bijective (nwg % 8 == 0)
    const size_t tm = (size_t)(wg / gridN) * 256;
    const size_t tn = (size_t)(wg % gridN) * 256;

    const int srow = tid >> 3;                 // 0..63
    const int slot = tid & 7;
    const int sc   = slot ^ (srow & 7);
    const short* pA = A + (tm + srow) * lda + sc * 8;
    const short* pB = B + (tn + srow) * ldb + sc * 8;
    const int ldst = srow * 64 + slot * 8;

    const int fr = lane & 15, kg = lane >> 4;
    const int wr = wave >> 2, wc = wave & 3;

    auto STAGE = [&](int t) {
        short* bufA = lds + (t & 1) * 32768;
        short* bufB = bufA + 16384;
        const size_t k0 = (size_t)t * 64;
        #pragma unroll
        for (int j = 0; j < 4; ++j) {
            gload_lds16(pA + (size_t)(j * 64) * lda + k0, bufA + j * 4096 + ldst);
            gload_lds16(pB + (size_t)(j * 64) * ldb + k0, bufB + j * 4096 + ldst);
        }
    };

    f4 acc[8][4];
    #pragma unroll
    for (int m = 0; m < 8; ++m)
        #pragma unroll
        for (int n = 0; n < 4; ++n)
            acc[m][n] = (f4){0.f, 0.f, 0.f, 0.f};

    STAGE(0);
    __syncthreads();

    for (int t = 0; t < nt; ++t) {
        if (t + 1 < nt) STAGE(t + 1);

        const short* bufA = lds + (t & 1) * 32768;
        const short* bufB = bufA + 16384;
        s8 af[2][8], bf[2][4];
        #pragma unroll
        for (int kh = 0; kh < 2; ++kh) {
            #pragma unroll
            for (int m = 0; m < 8; ++m) {
                const int row = wr * 128 + m * 16 + fr;
                const int c   = kh * 4 + kg;
                af[kh][m] = *(const s8*)(bufA + row * 64 + (c ^ (row & 7)) * 8);
            }
            #pragma unroll
            for (int n = 0; n < 4; ++n) {
                const int row = wc * 64 + n * 16 + fr;
                const int c   = kh * 4 + kg;
                bf[kh][n] = *(const s8*)(bufB + row * 64 + (c ^ (row & 7)) * 8);
            }
        }
        __builtin_amdgcn_s_setprio(1);
        #pragma unroll
        for (int kh = 0; kh < 2; ++kh)
            #pragma unroll
            for (int m = 0; m < 8; ++m)
                #pragma unroll
                for (int n = 0; n < 4; ++n)
                    acc[m][n] = __builtin_amdgcn_mfma_f32_16x16x32_bf16(
                        af[kh][m], bf[kh][n], acc[m][n], 0, 0, 0);
        __builtin_amdgcn_s_setprio(0);

        __syncthreads();
    }

    const int cg = lane >> 4, cl = lane & 15;
    #pragma unroll
    for (int m = 0; m < 8; ++m) {
        #pragma unroll
        for (int n = 0; n < 4; ++n) {
            const size_t grow = tm + wr * 128 + m * 16 + cg * 4;
            const size_t gcol = tn + wc * 64 + n * 16 + cl;
            float bv = 0.f;
            if constexpr (OUT == 0) { if (bias) bv = bias[gcol]; }
            #pragma unroll
            for (int i = 0; i < 4; ++i) {
                const float val = acc[m][n][i] + bv;
                if constexpr (OUT == 0)
                    Cf[(grow + i) * ldc + gcol] = val;
                else
                    Cs[(grow + i) * ldc + gcol] = f2bf(val);
            }
        }
    }
}

// fp32 -> bf16, 8 elements/thread (W only).
__global__ __launch_bounds__(256) void conv_bf16(const float* __restrict__ in,
                                                 short* __restrict__ out, int n8)
{
    const int i = blockIdx.x * 256 + threadIdx.x;
    if (i >= n8) return;
    f4 a = ((const f4*)in)[2 * i];
    f4 b = ((const f4*)in)[2 * i + 1];
    s8 w;
    w[0] = f2bf(a[0]); w[1] = f2bf(a[1]); w[2] = f2bf(a[2]); w[3] = f2bf(a[3]);
    w[4] = f2bf(b[0]); w[5] = f2bf(b[1]); w[6] = f2bf(b[2]); w[7] = f2bf(b[3]);
    ((s8*)out)[i] = w;
}

// ===========================================================================
// prep_batch: one launch per batch doing Q-conv, K-conv, V-transpose.
// ===========================================================================
__global__ __launch_bounds__(256) void prep_batch(
    const float* __restrict__ Qf, const float* __restrict__ Kf,
    const float* __restrict__ Vf,
    short* __restrict__ Qb, short* __restrict__ Kb, short* __restrict__ VT)
{
    const int tid = threadIdx.x;
    const int blk = blockIdx.x;

    if (blk < 4096) {
        const float* in = (blk < 2048) ? Qf : Kf;
        short* out      = (blk < 2048) ? Qb : Kb;
        const int i = (blk & 2047) * 256 + tid;
        f4 a = ((const f4*)in)[2 * i];
        f4 b = ((const f4*)in)[2 * i + 1];
        s8 w;
        w[0] = f2bf(a[0]); w[1] = f2bf(a[1]); w[2] = f2bf(a[2]); w[3] = f2bf(a[3]);
        w[4] = f2bf(b[0]); w[5] = f2bf(b[1]); w[6] = f2bf(b[2]); w[7] = f2bf(b[3]);
        ((s8*)out)[i] = w;
    } else {
        __shared__ float t[32][33];
        const int b2 = blk - 4096;
        const size_t k0 = (size_t)(b2 & 127) * 32;
        const size_t d0 = (size_t)(b2 >> 7) * 32;

        const int r = tid >> 3, c4 = (tid & 7) * 4;
        f4 x = *(const f4*)(Vf + (k0 + r) * DIM + d0 + c4);
        #pragma unroll
        for (int i = 0; i < 4; ++i) t[r][c4 + i] = x[i];
        __syncthreads();

        const int d = tid >> 3, kk = (tid & 7) * 4;
        s4 w;
        #pragma unroll
        for (int i = 0; i < 4; ++i) w[i] = f2bf(t[kk + i][d]);
        *(s4*)(VT + (d0 + d) * SEQ + k0 + kk) = w;
    }
}

// Row softmax over 4096 bf16 scores (packed, ld 4096), y-batched over 4
// score slices of SEQ*SEQ. Validated structure (round 12); bit-shift loads.
__global__ __launch_bounds__(256) void softmax_rows_bf(short* __restrict__ scores)
{
    const int tid = threadIdx.x;
    short* srow = scores + (size_t)blockIdx.y * SEQ * SEQ + (size_t)blockIdx.x * SEQ;
    const float SCALE = 0.03125f;

    float v[16];
    float mx = -3.4e38f;
    #pragma unroll
    for (int j = 0; j < 4; ++j) {
        s4 h = *(const s4*)(srow + (size_t)(j * 256 + tid) * 4);
        #pragma unroll
        for (int i = 0; i < 4; ++i) {
            const float f = bf2f(h[i]) * SCALE;
            v[j * 4 + i] = f;
            mx = fmaxf(mx, f);
        }
    }
    #pragma unroll
    for (int o = 32; o > 0; o >>= 1) mx = fmaxf(mx, __shfl_xor(mx, o));
    __shared__ float red[4];
    if ((tid & 63) == 0) red[tid >> 6] = mx;
    __syncthreads();
    mx = fmaxf(fmaxf(red[0], red[1]), fmaxf(red[2], red[3]));

    float sum = 0.f;
    #pragma unroll
    for (int j = 0; j < 16; ++j) {
        const float e = __expf(v[j] - mx);
        v[j] = e;
        sum += e;
    }
    #pragma unroll
    for (int o = 32; o > 0; o >>= 1) sum += __shfl_xor(sum, o);
    __syncthreads();
    if ((tid & 63) == 0) red[tid >> 6] = sum;
    __syncthreads();
    const float inv = 1.f / (red[0] + red[1] + red[2] + red[3]);

    #pragma unroll
    for (int j = 0; j < 4; ++j) {
        s4 w;
        #pragma unroll
        for (int i = 0; i < 4; ++i) w[i] = f2bf(v[j * 4 + i] * inv);
        *(s4*)(srow + (size_t)(j * 256 + tid) * 4) = w;
    }
}

extern "C" void kernel_launch(void* const* d_in, const int* in_sizes, int n_in,
                              void* d_out, int out_size, void* d_ws, size_t ws_size,
                              hipStream_t stream) {
    const float* Q    = (const float*)d_in[0];
    const float* Km   = (const float*)d_in[1];
    const float* V    = (const float*)d_in[2];
    const float* W    = (const float*)d_in[3];
    const float* bias = (const float*)d_in[4];
    float* out = (float*)d_out;

    // ws: ctx bf16 64MB | VT4 32MB | Qb 8MB | Kb 8MB | Wb 2MB  (= 114 MB)
    short* ctx = (short*)d_ws;
    short* VT4 = ctx + (size_t)NB * SEQ * DIM;
    short* Qb  = VT4 + (size_t)4 * DIM * SEQ;
    short* Kb  = Qb + (size_t)SEQ * DIM;
    short* Wb  = Kb + (size_t)SEQ * DIM;
    // d_out holds bf16 scores for a group of 4 batches: 4 x 32 MB = 128 MiB
    // (== out_size * 4 B exactly); overwritten by the final fp32 proj.
    short* scoresB = (short*)d_out;

    const dim3 blk256(256), blk512(512);
    conv_bf16<<<DIM * DIM / 2048, blk256, 0, stream>>>(W, Wb, DIM * DIM / 8);

    for (int g = 0; g < 2; ++g) {
        for (int b4 = 0; b4 < 4; ++b4) {
            const int b = g * 4 + b4;
            const float* Qf = Q  + (size_t)b * SEQ * DIM;
            const float* Kf = Km + (size_t)b * SEQ * DIM;
            const float* Vf = V  + (size_t)b * SEQ * DIM;

            prep_batch<<<dim3(8192), blk256, 0, stream>>>(
                Qf, Kf, Vf, Qb, Kb, VT4 + (size_t)b4 * DIM * SEQ);

            // scores(bf16, raw) = Qb * Kb^T into slice b4
            gemm256<2><<<dim3(256, 1), blk512, 0, stream>>>(
                Qb, DIM, 0, Kb, DIM, 0,
                scoresB + (size_t)b4 * SEQ * SEQ, SEQ, 0,
                nullptr, DIM / 64, 16);
        }
        // softmax over all 4 slices
        softmax_rows_bf<<<dim3(SEQ, 4), blk256, 0, stream>>>(scoresB);

        // ctx = P * VT^T, y-batched over 4 (grid 64x4 = 256 wgs)
        gemm256<2><<<dim3(64, 4), blk512, 0, stream>>>(
            scoresB, SEQ, (size_t)SEQ * SEQ,
            VT4, SEQ, (size_t)DIM * SEQ,
            ctx + (size_t)g * 4 * SEQ * DIM, DIM, (size_t)SEQ * DIM,
            nullptr, SEQ / 64, 4);
    }

    // proj: out = ctx * W^T + bias
    gemm256<0><<<dim3(512, 1), blk512, 0, stream>>>(
        ctx, DIM, 0, Wb, DIM, 0, out, DIM, 0, bias, DIM / 64, 4);
}